// Round 2
// baseline (1347.667 us; speedup 1.0000x reference)
//
#include <hip/hip_runtime.h>
#include <cstdint>

#define NTOK 8192
#define CDIM 1024
#define HDIM 1408
#define HSDIM 2816
#define NEXP 8

typedef __attribute__((ext_vector_type(8))) short s8v;
typedef __attribute__((ext_vector_type(4))) float f4v;

__device__ __forceinline__ unsigned short f2bf(float f) {
    unsigned int u = __float_as_uint(f);
    unsigned int r = (u + 0x7fffu + ((u >> 16) & 1u)) >> 16;  // RNE
    return (unsigned short)r;
}

__device__ __forceinline__ void g2l16(unsigned short* lds, const unsigned short* g) {
    __builtin_amdgcn_global_load_lds(
        (const __attribute__((address_space(1))) unsigned int*)g,
        (__attribute__((address_space(3))) unsigned int*)lds, 16, 0, 0);
}

// ---------------- conversion kernels ----------------

__global__ void cvt_bf16_kernel(const float4* __restrict__ in, ushort4* __restrict__ out, int n4) {
    int i = blockIdx.x * blockDim.x + threadIdx.x;
    if (i < n4) {
        float4 v = in[i];
        ushort4 o;
        o.x = f2bf(v.x); o.y = f2bf(v.y); o.z = f2bf(v.z); o.w = f2bf(v.w);
        out[i] = o;
    }
}

// in: fp32 [batch][R][Cc] -> out: bf16 [batch][Cc][R]
__global__ void transpose_cvt_kernel(const float* __restrict__ in, unsigned short* __restrict__ out,
                                     int R, int Cc) {
    __shared__ unsigned short tile[32][33];
    const size_t bstride = (size_t)R * Cc;
    const float* bin = in + blockIdx.z * bstride;
    unsigned short* bout = out + blockIdx.z * bstride;
    int c0 = blockIdx.x * 32, r0 = blockIdx.y * 32;
    int x = threadIdx.x, y = threadIdx.y;  // 32 x 8
#pragma unroll
    for (int i = 0; i < 4; i++) {
        int r = r0 + y + i * 8;
        tile[y + i * 8][x] = f2bf(bin[(size_t)r * Cc + c0 + x]);
    }
    __syncthreads();
#pragma unroll
    for (int i = 0; i < 4; i++) {
        int cc = y + i * 8;
        bout[(size_t)(c0 + cc) * R + r0 + x] = tile[x][cc];
    }
}

// ---------------- router ----------------
__global__ void router_kernel(const float* __restrict__ x, const float* __restrict__ Wg,
                              int* __restrict__ idxK, float* __restrict__ probK,
                              int* __restrict__ meta) {
    int t = blockIdx.x;
    int lane = threadIdx.x;
    const float* xr = x + (size_t)t * CDIM;
    float acc[NEXP];
#pragma unroll
    for (int e = 0; e < NEXP; e++) acc[e] = 0.f;
    for (int c = lane; c < CDIM; c += 64) {
        float xv = xr[c];
        const float* wr = Wg + c * NEXP;
#pragma unroll
        for (int e = 0; e < NEXP; e++) acc[e] += xv * wr[e];
    }
#pragma unroll
    for (int e = 0; e < NEXP; e++)
        for (int off = 32; off > 0; off >>= 1)
            acc[e] += __shfl_down(acc[e], off, 64);
    if (lane == 0) {
        int b0 = 0; float v0 = acc[0];
#pragma unroll
        for (int e = 1; e < NEXP; e++) if (acc[e] > v0) { v0 = acc[e]; b0 = e; }
        int b1 = -1; float v1 = -1e30f;
#pragma unroll
        for (int e = 0; e < NEXP; e++) if (e != b0 && acc[e] > v1) { v1 = acc[e]; b1 = e; }
        float p0 = 1.f / (1.f + __expf(v1 - v0));
        idxK[2 * t] = b0; idxK[2 * t + 1] = b1;
        probK[2 * t] = p0; probK[2 * t + 1] = 1.f - p0;
        atomicAdd(&meta[b0], 1);
        atomicAdd(&meta[b1], 1);
    }
}

// meta: [0..7] counts, [8..15] offsets, [16..23] cursor
__global__ void offsets_kernel(int* meta) {
    int s = 0;
    for (int e = 0; e < NEXP; e++) { meta[8 + e] = s; meta[16 + e] = s; s += meta[e]; }
}

__global__ void fill_kernel(const int* __restrict__ idxK, const float* __restrict__ probK,
                            int* __restrict__ meta, int* __restrict__ rowT, float* __restrict__ rowW) {
    int t = blockIdx.x * 256 + threadIdx.x;
    if (t >= NTOK) return;
#pragma unroll
    for (int k = 0; k < 2; k++) {
        int e = idxK[2 * t + k];
        int p = atomicAdd(&meta[16 + e], 1);
        rowT[p] = t;
        rowW[p] = probK[2 * t + k];
    }
}

// ---------------- fused gate GEMM: H = silu(A@W1) * (A@W2) ----------------
// BM=128, BN=64, BK=32. 256 threads = 4 waves in 2x2.
// LDS layout is fragment-linear: window = 16-row tile (1024B), slot = (row&15) + 16*kchunk.
// Staged via swizzled global fetch so all ds_read_b128 are lane-linear (0 bank conflicts).
template <bool GATHER>
__global__ __launch_bounds__(256) void gemm12_kernel(
    const unsigned short* __restrict__ A, const unsigned short* __restrict__ B1g,
    const unsigned short* __restrict__ B2g, unsigned short* __restrict__ Hout,
    int N, int K, int Mdir, const int* __restrict__ rowT, const int* __restrict__ meta) {
    const int e = GATHER ? blockIdx.z : 0;
    const int M = GATHER ? meta[e] : Mdir;
    const int base = GATHER ? meta[8 + e] : 0;
    const int m0 = blockIdx.x * 128;
    if (m0 >= M) return;
    const int n0 = blockIdx.y * 64;

    __shared__ unsigned short As[128 * 32];
    __shared__ unsigned short Bs1[64 * 32];
    __shared__ unsigned short Bs2[64 * 32];

    const int tid = threadIdx.x;
    // fragment-linear staging coords: row within 64-row round, k-chunk within BK=32
    const int r4 = ((tid >> 6) << 4) | (tid & 15);
    const int c4 = (tid >> 4) & 3;

    int am0 = m0 + r4;        am0 = am0 < M ? am0 : M - 1;
    int am1 = m0 + 64 + r4;   am1 = am1 < M ? am1 : M - 1;
    long ar0, ar1;
    if (GATHER) { ar0 = rowT[base + am0]; ar1 = rowT[base + am1]; }
    else        { ar0 = am0;              ar1 = am1; }

    const unsigned short* a0p = A + (size_t)ar0 * K + c4 * 8;
    const unsigned short* a1p = A + (size_t)ar1 * K + c4 * 8;
    const unsigned short* b1p = B1g + (size_t)e * N * K + (size_t)(n0 + r4) * K + c4 * 8;
    const unsigned short* b2p = B2g + (size_t)e * N * K + (size_t)(n0 + r4) * K + c4 * 8;
    unsigned short* lA0 = As + tid * 8;
    unsigned short* lA1 = As + 2048 + tid * 8;
    unsigned short* lB1 = Bs1 + tid * 8;
    unsigned short* lB2 = Bs2 + tid * 8;

    const int w = tid >> 6, lane = tid & 63;
    const int wm = (w >> 1) * 64, wn = (w & 1) * 32;
    const int quad = lane >> 4, l15 = lane & 15;

    f4v acc1[4][2], acc2[4][2];
#pragma unroll
    for (int i = 0; i < 4; i++)
#pragma unroll
        for (int j = 0; j < 2; j++) {
            f4v z = {0.f, 0.f, 0.f, 0.f};
            acc1[i][j] = z; acc2[i][j] = z;
        }

    for (int k0 = 0; k0 < K; k0 += 32) {
        g2l16(lA0, a0p + k0);
        g2l16(lA1, a1p + k0);
        g2l16(lB1, b1p + k0);
        g2l16(lB2, b2p + k0);
        __syncthreads();
        s8v af[4], bf1[2], bf2[2];
#pragma unroll
        for (int mt = 0; mt < 4; mt++)
            af[mt] = *(const s8v*)(As + (wm + mt * 16) * 32 + lane * 8);
#pragma unroll
        for (int nt = 0; nt < 2; nt++) {
            bf1[nt] = *(const s8v*)(Bs1 + (wn + nt * 16) * 32 + lane * 8);
            bf2[nt] = *(const s8v*)(Bs2 + (wn + nt * 16) * 32 + lane * 8);
        }
#pragma unroll
        for (int mt = 0; mt < 4; mt++)
#pragma unroll
            for (int nt = 0; nt < 2; nt++) {
                acc1[mt][nt] = __builtin_amdgcn_mfma_f32_16x16x32_bf16(af[mt], bf1[nt], acc1[mt][nt], 0, 0, 0);
                acc2[mt][nt] = __builtin_amdgcn_mfma_f32_16x16x32_bf16(af[mt], bf2[nt], acc2[mt][nt], 0, 0, 0);
            }
        __syncthreads();
    }

#pragma unroll
    for (int mt = 0; mt < 4; mt++) {
#pragma unroll
        for (int r = 0; r < 4; r++) {
            int gm = m0 + wm + mt * 16 + quad * 4 + r;
            if (gm < M) {
                size_t rowoff = (size_t)(base + gm) * N;
#pragma unroll
                for (int nt = 0; nt < 2; nt++) {
                    float z1 = acc1[mt][nt][r];
                    float z2 = acc2[mt][nt][r];
                    float hv = (z1 / (1.f + __expf(-z1))) * z2;
                    Hout[rowoff + n0 + wn + nt * 16 + l15] = f2bf(hv);
                }
            }
        }
    }
}

// ---------------- down-proj GEMM: Out = H @ W3 (N fixed = 1024) ----------------
// BM=128, BN=128, BK=32. Same fragment-linear LDS layout.
template <bool SCATTER>
__global__ __launch_bounds__(256) void gemm3_kernel(
    const unsigned short* __restrict__ A, const unsigned short* __restrict__ Bg,
    float* __restrict__ Out, int K, int Mdir,
    const int* __restrict__ rowT, const float* __restrict__ rowW, const int* __restrict__ meta) {
    const int e = SCATTER ? blockIdx.z : 0;
    const int M = SCATTER ? meta[e] : Mdir;
    const int base = SCATTER ? meta[8 + e] : 0;
    const int m0 = blockIdx.x * 128;
    if (m0 >= M) return;
    const int n0 = blockIdx.y * 128;

    __shared__ unsigned short As[128 * 32];
    __shared__ unsigned short Bs[128 * 32];

    const int tid = threadIdx.x;
    const int r4 = ((tid >> 6) << 4) | (tid & 15);
    const int c4 = (tid >> 4) & 3;

    int am0 = m0 + r4;       am0 = am0 < M ? am0 : M - 1;
    int am1 = m0 + 64 + r4;  am1 = am1 < M ? am1 : M - 1;
    const unsigned short* a0p = A + (size_t)(base + am0) * K + c4 * 8;
    const unsigned short* a1p = A + (size_t)(base + am1) * K + c4 * 8;
    const unsigned short* b0p = Bg + (size_t)e * 1024 * K + (size_t)(n0 + r4) * K + c4 * 8;
    const unsigned short* b1p = b0p + (size_t)64 * K;
    unsigned short* lA0 = As + tid * 8;
    unsigned short* lA1 = As + 2048 + tid * 8;
    unsigned short* lB0 = Bs + tid * 8;
    unsigned short* lB1 = Bs + 2048 + tid * 8;

    const int w = tid >> 6, lane = tid & 63;
    const int wm = (w >> 1) * 64, wn = (w & 1) * 64;
    const int quad = lane >> 4, l15 = lane & 15;

    f4v acc[4][4];
#pragma unroll
    for (int i = 0; i < 4; i++)
#pragma unroll
        for (int j = 0; j < 4; j++) {
            f4v z = {0.f, 0.f, 0.f, 0.f};
            acc[i][j] = z;
        }

    for (int k0 = 0; k0 < K; k0 += 32) {
        g2l16(lA0, a0p + k0);
        g2l16(lA1, a1p + k0);
        g2l16(lB0, b0p + k0);
        g2l16(lB1, b1p + k0);
        __syncthreads();
        s8v af[4], bf[4];
#pragma unroll
        for (int mt = 0; mt < 4; mt++)
            af[mt] = *(const s8v*)(As + (wm + mt * 16) * 32 + lane * 8);
#pragma unroll
        for (int nt = 0; nt < 4; nt++)
            bf[nt] = *(const s8v*)(Bs + (wn + nt * 16) * 32 + lane * 8);
#pragma unroll
        for (int mt = 0; mt < 4; mt++)
#pragma unroll
            for (int nt = 0; nt < 4; nt++)
                acc[mt][nt] = __builtin_amdgcn_mfma_f32_16x16x32_bf16(af[mt], bf[nt], acc[mt][nt], 0, 0, 0);
        __syncthreads();
    }

#pragma unroll
    for (int mt = 0; mt < 4; mt++) {
#pragma unroll
        for (int r = 0; r < 4; r++) {
            int gm = m0 + wm + mt * 16 + quad * 4 + r;
            if (gm < M) {
                if (SCATTER) {
                    int rr = base + gm;
                    int t = rowT[rr];
                    float wgt = rowW[rr];
                    size_t o = (size_t)t * 1024 + n0 + wn + l15;
#pragma unroll
                    for (int nt = 0; nt < 4; nt++)
                        atomicAdd(&Out[o + nt * 16], wgt * acc[mt][nt][r]);
                } else {
                    size_t o = (size_t)gm * 1024 + n0 + wn + l15;
#pragma unroll
                    for (int nt = 0; nt < 4; nt++)
                        Out[o + nt * 16] = acc[mt][nt][r];
                }
            }
        }
    }
}

// ---------------- launch ----------------

extern "C" void kernel_launch(void* const* d_in, const int* in_sizes, int n_in,
                              void* d_out, int out_size, void* d_ws, size_t ws_size,
                              hipStream_t stream) {
    const float* x   = (const float*)d_in[0];
    const float* Wg  = (const float*)d_in[1];
    const float* W1  = (const float*)d_in[2];
    const float* W2  = (const float*)d_in[3];
    const float* W3  = (const float*)d_in[4];
    const float* Ws1 = (const float*)d_in[5];
    const float* Ws2 = (const float*)d_in[6];
    const float* Ws3 = (const float*)d_in[7];
    float* out = (float*)d_out;

    char* p = (char*)d_ws;
    auto carve = [&](size_t bytes) {
        char* r = p;
        p += (bytes + 255) & ~(size_t)255;
        return r;
    };
    unsigned short* xb   = (unsigned short*)carve((size_t)NTOK * CDIM * 2);
    unsigned short* w1t  = (unsigned short*)carve((size_t)NEXP * HDIM * CDIM * 2);
    unsigned short* w2t  = (unsigned short*)carve((size_t)NEXP * HDIM * CDIM * 2);
    unsigned short* w3t  = (unsigned short*)carve((size_t)NEXP * CDIM * HDIM * 2);
    unsigned short* ws1t = (unsigned short*)carve((size_t)HSDIM * CDIM * 2);
    unsigned short* ws2t = (unsigned short*)carve((size_t)HSDIM * CDIM * 2);
    unsigned short* ws3t = (unsigned short*)carve((size_t)CDIM * HSDIM * 2);
    unsigned short* hbuf = (unsigned short*)carve((size_t)2 * NTOK * HDIM * 2);
    int*   idxK  = (int*)carve((size_t)NTOK * 2 * 4);
    float* probK = (float*)carve((size_t)NTOK * 2 * 4);
    int*   rowT  = (int*)carve((size_t)2 * NTOK * 4);
    float* rowW  = (float*)carve((size_t)2 * NTOK * 4);
    int*   meta  = (int*)carve(256);

    dim3 tb(32, 8);
    cvt_bf16_kernel<<<(NTOK * CDIM / 4 + 255) / 256, 256, 0, stream>>>((const float4*)x, (ushort4*)xb, NTOK * CDIM / 4);
    transpose_cvt_kernel<<<dim3(HDIM / 32, CDIM / 32, NEXP), tb, 0, stream>>>(W1, w1t, CDIM, HDIM);
    transpose_cvt_kernel<<<dim3(HDIM / 32, CDIM / 32, NEXP), tb, 0, stream>>>(W2, w2t, CDIM, HDIM);
    transpose_cvt_kernel<<<dim3(CDIM / 32, HDIM / 32, NEXP), tb, 0, stream>>>(W3, w3t, HDIM, CDIM);
    transpose_cvt_kernel<<<dim3(HSDIM / 32, CDIM / 32, 1), tb, 0, stream>>>(Ws1, ws1t, CDIM, HSDIM);
    transpose_cvt_kernel<<<dim3(HSDIM / 32, CDIM / 32, 1), tb, 0, stream>>>(Ws2, ws2t, CDIM, HSDIM);
    transpose_cvt_kernel<<<dim3(CDIM / 32, HSDIM / 32, 1), tb, 0, stream>>>(Ws3, ws3t, HSDIM, CDIM);

    hipMemsetAsync(meta, 0, 256, stream);
    router_kernel<<<NTOK, 64, 0, stream>>>(x, Wg, idxK, probK, meta);
    offsets_kernel<<<1, 1, 0, stream>>>(meta);
    fill_kernel<<<NTOK / 256, 256, 0, stream>>>(idxK, probK, meta, rowT, rowW);

    gemm12_kernel<false><<<dim3(NTOK / 128, HSDIM / 64), 256, 0, stream>>>(
        xb, ws1t, ws2t, hbuf, HSDIM, CDIM, NTOK, nullptr, nullptr);
    gemm3_kernel<false><<<dim3(NTOK / 128, CDIM / 128), 256, 0, stream>>>(
        hbuf, ws3t, out, HSDIM, NTOK, nullptr, nullptr, nullptr);

    gemm12_kernel<true><<<dim3(NTOK / 128, HDIM / 64, NEXP), 256, 0, stream>>>(
        xb, w1t, w2t, hbuf, HDIM, CDIM, 0, rowT, meta);
    gemm3_kernel<true><<<dim3(NTOK / 128, CDIM / 128, NEXP), 256, 0, stream>>>(
        hbuf, w3t, out, HDIM, 0, rowT, rowW, meta);
}

// Round 3
// 1107.445 us; speedup vs baseline: 1.2169x; 1.2169x over previous
//
#include <hip/hip_runtime.h>
#include <cstdint>

#define NTOK 8192
#define CDIM 1024
#define HDIM 1408
#define HSDIM 2816
#define NEXP 8

typedef __attribute__((ext_vector_type(8))) short s8v;
typedef __attribute__((ext_vector_type(4))) float f4v;

__device__ __forceinline__ unsigned short f2bf(float f) {
    unsigned int u = __float_as_uint(f);
    unsigned int r = (u + 0x7fffu + ((u >> 16) & 1u)) >> 16;  // RNE
    return (unsigned short)r;
}

__device__ __forceinline__ void g2l16(unsigned short* lds, const unsigned short* g) {
    __builtin_amdgcn_global_load_lds(
        (const __attribute__((address_space(1))) unsigned int*)g,
        (__attribute__((address_space(3))) unsigned int*)lds, 16, 0, 0);
}

// ---------------- conversion kernels ----------------

__global__ void cvt_bf16_kernel(const float4* __restrict__ in, ushort4* __restrict__ out, int n4) {
    int i = blockIdx.x * blockDim.x + threadIdx.x;
    if (i < n4) {
        float4 v = in[i];
        ushort4 o;
        o.x = f2bf(v.x); o.y = f2bf(v.y); o.z = f2bf(v.z); o.w = f2bf(v.w);
        out[i] = o;
    }
}

// in: fp32 [batch][R][Cc] -> out: bf16 [batch][Cc][R]
__global__ void transpose_cvt_kernel(const float* __restrict__ in, unsigned short* __restrict__ out,
                                     int R, int Cc) {
    __shared__ unsigned short tile[32][33];
    const size_t bstride = (size_t)R * Cc;
    const float* bin = in + blockIdx.z * bstride;
    unsigned short* bout = out + blockIdx.z * bstride;
    int c0 = blockIdx.x * 32, r0 = blockIdx.y * 32;
    int x = threadIdx.x, y = threadIdx.y;  // 32 x 8
#pragma unroll
    for (int i = 0; i < 4; i++) {
        int r = r0 + y + i * 8;
        tile[y + i * 8][x] = f2bf(bin[(size_t)r * Cc + c0 + x]);
    }
    __syncthreads();
#pragma unroll
    for (int i = 0; i < 4; i++) {
        int cc = y + i * 8;
        bout[(size_t)(c0 + cc) * R + r0 + x] = tile[x][cc];
    }
}

// ---------------- router ----------------
__global__ void router_kernel(const float* __restrict__ x, const float* __restrict__ Wg,
                              int* __restrict__ idxK, float* __restrict__ probK,
                              int* __restrict__ meta) {
    int t = blockIdx.x;
    int lane = threadIdx.x;
    const float* xr = x + (size_t)t * CDIM;
    float acc[NEXP];
#pragma unroll
    for (int e = 0; e < NEXP; e++) acc[e] = 0.f;
    for (int c = lane; c < CDIM; c += 64) {
        float xv = xr[c];
        const float* wr = Wg + c * NEXP;
#pragma unroll
        for (int e = 0; e < NEXP; e++) acc[e] += xv * wr[e];
    }
#pragma unroll
    for (int e = 0; e < NEXP; e++)
        for (int off = 32; off > 0; off >>= 1)
            acc[e] += __shfl_down(acc[e], off, 64);
    if (lane == 0) {
        int b0 = 0; float v0 = acc[0];
#pragma unroll
        for (int e = 1; e < NEXP; e++) if (acc[e] > v0) { v0 = acc[e]; b0 = e; }
        int b1 = -1; float v1 = -1e30f;
#pragma unroll
        for (int e = 0; e < NEXP; e++) if (e != b0 && acc[e] > v1) { v1 = acc[e]; b1 = e; }
        float p0 = 1.f / (1.f + __expf(v1 - v0));
        idxK[2 * t] = b0; idxK[2 * t + 1] = b1;
        probK[2 * t] = p0; probK[2 * t + 1] = 1.f - p0;
        atomicAdd(&meta[b0], 1);
        atomicAdd(&meta[b1], 1);
    }
}

// meta: [0..7] counts, [8..15] offsets, [16..23] cursor
__global__ void offsets_kernel(int* meta) {
    int s = 0;
    for (int e = 0; e < NEXP; e++) { meta[8 + e] = s; meta[16 + e] = s; s += meta[e]; }
}

__global__ void fill_kernel(const int* __restrict__ idxK, const float* __restrict__ probK,
                            int* __restrict__ meta, int* __restrict__ rowT, float* __restrict__ rowW) {
    int t = blockIdx.x * 256 + threadIdx.x;
    if (t >= NTOK) return;
#pragma unroll
    for (int k = 0; k < 2; k++) {
        int e = idxK[2 * t + k];
        int p = atomicAdd(&meta[16 + e], 1);
        rowT[p] = t;
        rowW[p] = probK[2 * t + k];
    }
}

// ---------------- merged fused gate GEMM: H = silu(A@W1) * (A@W2) ----------------
// z<8: expert e (gathered rows, N=1408). z==8: shared (direct rows, N=2816).
// BM=128, BN=64, BK=64. 256 threads = 4 waves (2x2).
// LDS row-major [row][64] with XOR chunk swizzle (chunk' = chunk ^ (row&7)):
// staging keeps 8 consecutive lanes on one contiguous 64B global segment
// (R2 lesson), reads are conflict-free.
__global__ __launch_bounds__(256) void gemm12_kernel(
    const unsigned short* __restrict__ xb,
    const unsigned short* __restrict__ w1, const unsigned short* __restrict__ w2,
    const unsigned short* __restrict__ ws1, const unsigned short* __restrict__ ws2,
    unsigned short* __restrict__ hE, unsigned short* __restrict__ hS,
    const int* __restrict__ rowT, const int* __restrict__ meta) {
    const int z = blockIdx.z;
    const bool SH = (z == 8);
    const int N = SH ? HSDIM : HDIM;
    const int n0 = blockIdx.y * 64;
    if (n0 >= N) return;
    const int M = SH ? NTOK : meta[z];
    const int base = SH ? 0 : meta[8 + z];
    const int m0 = blockIdx.x * 128;
    if (m0 >= M) return;

    const unsigned short* B1 = SH ? ws1 : w1 + (size_t)z * HDIM * CDIM;
    const unsigned short* B2 = SH ? ws2 : w2 + (size_t)z * HDIM * CDIM;

    __shared__ unsigned short As[128 * 64];   // 16 KB
    __shared__ unsigned short Bs1[64 * 64];   // 8 KB
    __shared__ unsigned short Bs2[64 * 64];   // 8 KB

    const int tid = threadIdx.x;
    const int srow = tid >> 3;          // 0..31, staging row within 32-row group
    const int sc = tid & 7;             // dest chunk

    // A: 4 row-groups
    const unsigned short* ap[4];
#pragma unroll
    for (int j = 0; j < 4; j++) {
        int rloc = srow + 32 * j;
        int am = m0 + rloc; am = am < M ? am : M - 1;
        long ar = SH ? am : rowT[base + am];
        ap[j] = xb + (size_t)ar * CDIM + ((sc ^ (rloc & 7)) << 3);
    }
    // B1/B2: 2 row-groups each
    const unsigned short *b1p[2], *b2p[2];
#pragma unroll
    for (int j = 0; j < 2; j++) {
        int rloc = srow + 32 * j;
        int bn = n0 + rloc;
        int co = (sc ^ (rloc & 7)) << 3;
        b1p[j] = B1 + (size_t)bn * CDIM + co;
        b2p[j] = B2 + (size_t)bn * CDIM + co;
    }

    const int w = tid >> 6, lane = tid & 63;
    const int wm = (w >> 1) * 64, wn = (w & 1) * 32;
    const int quad = lane >> 4, l15 = lane & 15;
    const int key = l15 & 7;

    f4v acc1[4][2], acc2[4][2];
#pragma unroll
    for (int i = 0; i < 4; i++)
#pragma unroll
        for (int j = 0; j < 2; j++) {
            f4v zz = {0.f, 0.f, 0.f, 0.f};
            acc1[i][j] = zz; acc2[i][j] = zz;
        }

    for (int k0 = 0; k0 < CDIM; k0 += 64) {
#pragma unroll
        for (int j = 0; j < 4; j++) g2l16(As + j * 2048 + tid * 8, ap[j] + k0);
#pragma unroll
        for (int j = 0; j < 2; j++) {
            g2l16(Bs1 + j * 2048 + tid * 8, b1p[j] + k0);
            g2l16(Bs2 + j * 2048 + tid * 8, b2p[j] + k0);
        }
        __syncthreads();
#pragma unroll
        for (int ksub = 0; ksub < 2; ksub++) {
            const int cx = (((ksub << 2) | quad) ^ key) << 3;
            s8v af[4], bf1[2], bf2[2];
#pragma unroll
            for (int mt = 0; mt < 4; mt++)
                af[mt] = *(const s8v*)(As + (wm + mt * 16 + l15) * 64 + cx);
#pragma unroll
            for (int nt = 0; nt < 2; nt++) {
                bf1[nt] = *(const s8v*)(Bs1 + (wn + nt * 16 + l15) * 64 + cx);
                bf2[nt] = *(const s8v*)(Bs2 + (wn + nt * 16 + l15) * 64 + cx);
            }
#pragma unroll
            for (int mt = 0; mt < 4; mt++)
#pragma unroll
                for (int nt = 0; nt < 2; nt++) {
                    acc1[mt][nt] = __builtin_amdgcn_mfma_f32_16x16x32_bf16(af[mt], bf1[nt], acc1[mt][nt], 0, 0, 0);
                    acc2[mt][nt] = __builtin_amdgcn_mfma_f32_16x16x32_bf16(af[mt], bf2[nt], acc2[mt][nt], 0, 0, 0);
                }
        }
        __syncthreads();
    }

#pragma unroll
    for (int mt = 0; mt < 4; mt++) {
#pragma unroll
        for (int r = 0; r < 4; r++) {
            int gm = m0 + wm + mt * 16 + quad * 4 + r;
            if (gm < M) {
                unsigned short* hrow = SH ? hS + (size_t)gm * HSDIM
                                          : hE + (size_t)(base + gm) * HDIM;
#pragma unroll
                for (int nt = 0; nt < 2; nt++) {
                    float z1 = acc1[mt][nt][r];
                    float z2 = acc2[mt][nt][r];
                    float hv = (z1 / (1.f + __expf(-z1))) * z2;
                    hrow[n0 + wn + nt * 16 + l15] = f2bf(hv);
                }
            }
        }
    }
}

// ---------------- merged down-proj GEMM: Out += w * (H @ W3) ----------------
// z<8: expert (A=hE, K=1408, weight=rowW). z==8: shared (A=hS, K=2816, weight=1).
// BM=128, BN=128, BK=64. All writes atomicAdd onto zeroed Out (order-free).
__global__ __launch_bounds__(256) void gemm3_kernel(
    const unsigned short* __restrict__ hE, const unsigned short* __restrict__ hS,
    const unsigned short* __restrict__ w3, const unsigned short* __restrict__ ws3,
    float* __restrict__ Out,
    const int* __restrict__ rowT, const float* __restrict__ rowW, const int* __restrict__ meta) {
    const int z = blockIdx.z;
    const bool SH = (z == 8);
    const int M = SH ? NTOK : meta[z];
    const int base = SH ? 0 : meta[8 + z];
    const int m0 = blockIdx.x * 128;
    if (m0 >= M) return;
    const int n0 = blockIdx.y * 128;
    const int K = SH ? HSDIM : HDIM;
    const unsigned short* A = SH ? hS : hE;
    const unsigned short* B = SH ? ws3 : w3 + (size_t)z * CDIM * HDIM;

    __shared__ unsigned short As[128 * 64];   // 16 KB
    __shared__ unsigned short Bs[128 * 64];   // 16 KB

    const int tid = threadIdx.x;
    const int srow = tid >> 3;
    const int sc = tid & 7;

    const unsigned short *ap[4], *bp[4];
#pragma unroll
    for (int j = 0; j < 4; j++) {
        int rloc = srow + 32 * j;
        int am = m0 + rloc; am = am < M ? am : M - 1;
        int co = (sc ^ (rloc & 7)) << 3;
        ap[j] = A + (size_t)(base + am) * K + co;
        bp[j] = B + (size_t)(n0 + rloc) * K + co;
    }

    const int w = tid >> 6, lane = tid & 63;
    const int wm = (w >> 1) * 64, wn = (w & 1) * 64;
    const int quad = lane >> 4, l15 = lane & 15;
    const int key = l15 & 7;

    f4v acc[4][4];
#pragma unroll
    for (int i = 0; i < 4; i++)
#pragma unroll
        for (int j = 0; j < 4; j++) {
            f4v zz = {0.f, 0.f, 0.f, 0.f};
            acc[i][j] = zz;
        }

    for (int k0 = 0; k0 < K; k0 += 64) {
#pragma unroll
        for (int j = 0; j < 4; j++) {
            g2l16(As + j * 2048 + tid * 8, ap[j] + k0);
            g2l16(Bs + j * 2048 + tid * 8, bp[j] + k0);
        }
        __syncthreads();
#pragma unroll
        for (int ksub = 0; ksub < 2; ksub++) {
            const int cx = (((ksub << 2) | quad) ^ key) << 3;
            s8v af[4], bf[4];
#pragma unroll
            for (int mt = 0; mt < 4; mt++)
                af[mt] = *(const s8v*)(As + (wm + mt * 16 + l15) * 64 + cx);
#pragma unroll
            for (int nt = 0; nt < 4; nt++)
                bf[nt] = *(const s8v*)(Bs + (wn + nt * 16 + l15) * 64 + cx);
#pragma unroll
            for (int mt = 0; mt < 4; mt++)
#pragma unroll
                for (int nt = 0; nt < 4; nt++)
                    acc[mt][nt] = __builtin_amdgcn_mfma_f32_16x16x32_bf16(af[mt], bf[nt], acc[mt][nt], 0, 0, 0);
        }
        __syncthreads();
    }

#pragma unroll
    for (int mt = 0; mt < 4; mt++) {
#pragma unroll
        for (int r = 0; r < 4; r++) {
            int gm = m0 + wm + mt * 16 + quad * 4 + r;
            if (gm < M) {
                int t; float wgt;
                if (SH) { t = gm; wgt = 1.f; }
                else    { int rr = base + gm; t = rowT[rr]; wgt = rowW[rr]; }
                size_t o = (size_t)t * CDIM + n0 + wn + l15;
#pragma unroll
                for (int nt = 0; nt < 4; nt++)
                    atomicAdd(&Out[o + nt * 16], wgt * acc[mt][nt][r]);
            }
        }
    }
}

// ---------------- launch ----------------

extern "C" void kernel_launch(void* const* d_in, const int* in_sizes, int n_in,
                              void* d_out, int out_size, void* d_ws, size_t ws_size,
                              hipStream_t stream) {
    const float* x   = (const float*)d_in[0];
    const float* Wg  = (const float*)d_in[1];
    const float* W1  = (const float*)d_in[2];
    const float* W2  = (const float*)d_in[3];
    const float* W3  = (const float*)d_in[4];
    const float* Ws1 = (const float*)d_in[5];
    const float* Ws2 = (const float*)d_in[6];
    const float* Ws3 = (const float*)d_in[7];
    float* out = (float*)d_out;

    char* p = (char*)d_ws;
    auto carve = [&](size_t bytes) {
        char* r = p;
        p += (bytes + 255) & ~(size_t)255;
        return r;
    };
    unsigned short* xb   = (unsigned short*)carve((size_t)NTOK * CDIM * 2);
    unsigned short* w1t  = (unsigned short*)carve((size_t)NEXP * HDIM * CDIM * 2);
    unsigned short* w2t  = (unsigned short*)carve((size_t)NEXP * HDIM * CDIM * 2);
    unsigned short* w3t  = (unsigned short*)carve((size_t)NEXP * CDIM * HDIM * 2);
    unsigned short* ws1t = (unsigned short*)carve((size_t)HSDIM * CDIM * 2);
    unsigned short* ws2t = (unsigned short*)carve((size_t)HSDIM * CDIM * 2);
    unsigned short* ws3t = (unsigned short*)carve((size_t)CDIM * HSDIM * 2);
    unsigned short* hE   = (unsigned short*)carve((size_t)2 * NTOK * HDIM * 2);   // 46 MB
    unsigned short* hS   = (unsigned short*)carve((size_t)NTOK * HSDIM * 2);      // 46 MB
    int*   idxK  = (int*)carve((size_t)NTOK * 2 * 4);
    float* probK = (float*)carve((size_t)NTOK * 2 * 4);
    int*   rowT  = (int*)carve((size_t)2 * NTOK * 4);
    float* rowW  = (float*)carve((size_t)2 * NTOK * 4);
    int*   meta  = (int*)carve(256);

    // zero output (gemm3 is all-atomicAdd, order-free)
    hipMemsetAsync(out, 0, (size_t)out_size * 4, stream);

    dim3 tb(32, 8);
    cvt_bf16_kernel<<<(NTOK * CDIM / 4 + 255) / 256, 256, 0, stream>>>((const float4*)x, (ushort4*)xb, NTOK * CDIM / 4);
    transpose_cvt_kernel<<<dim3(HDIM / 32, CDIM / 32, NEXP), tb, 0, stream>>>(W1, w1t, CDIM, HDIM);
    transpose_cvt_kernel<<<dim3(HDIM / 32, CDIM / 32, NEXP), tb, 0, stream>>>(W2, w2t, CDIM, HDIM);
    transpose_cvt_kernel<<<dim3(CDIM / 32, HDIM / 32, NEXP), tb, 0, stream>>>(W3, w3t, HDIM, CDIM);
    transpose_cvt_kernel<<<dim3(HSDIM / 32, CDIM / 32, 1), tb, 0, stream>>>(Ws1, ws1t, CDIM, HSDIM);
    transpose_cvt_kernel<<<dim3(HSDIM / 32, CDIM / 32, 1), tb, 0, stream>>>(Ws2, ws2t, CDIM, HSDIM);
    transpose_cvt_kernel<<<dim3(CDIM / 32, HSDIM / 32, 1), tb, 0, stream>>>(Ws3, ws3t, HSDIM, CDIM);

    hipMemsetAsync(meta, 0, 256, stream);
    router_kernel<<<NTOK, 64, 0, stream>>>(x, Wg, idxK, probK, meta);
    offsets_kernel<<<1, 1, 0, stream>>>(meta);
    fill_kernel<<<NTOK / 256, 256, 0, stream>>>(idxK, probK, meta, rowT, rowW);

    // merged up-proj (experts z=0..7, shared z=8)
    gemm12_kernel<<<dim3(NTOK / 128, HSDIM / 64, NEXP + 1), 256, 0, stream>>>(
        xb, w1t, w2t, ws1t, ws2t, hE, hS, rowT, meta);
    // merged down-proj (all atomic)
    gemm3_kernel<<<dim3(NTOK / 128, CDIM / 128, NEXP + 1), 256, 0, stream>>>(
        hE, hS, w3t, ws3t, out, rowT, rowW, meta);
}

// Round 4
// 1019.305 us; speedup vs baseline: 1.3221x; 1.0865x over previous
//
#include <hip/hip_runtime.h>
#include <cstdint>

#define NTOK 8192
#define CDIM 1024
#define HDIM 1408
#define HSDIM 2816
#define NEXP 8

typedef __attribute__((ext_vector_type(8))) short s8v;
typedef __attribute__((ext_vector_type(4))) float f4v;

__device__ __forceinline__ unsigned short f2bf(float f) {
    unsigned int u = __float_as_uint(f);
    unsigned int r = (u + 0x7fffu + ((u >> 16) & 1u)) >> 16;  // RNE
    return (unsigned short)r;
}

__device__ __forceinline__ void g2l16(unsigned short* lds, const unsigned short* g) {
    __builtin_amdgcn_global_load_lds(
        (const __attribute__((address_space(1))) unsigned int*)g,
        (__attribute__((address_space(3))) unsigned int*)lds, 16, 0, 0);
}

// ---------------- conversion kernels ----------------

__global__ void cvt_bf16_kernel(const float4* __restrict__ in, ushort4* __restrict__ out, int n4) {
    int i = blockIdx.x * blockDim.x + threadIdx.x;
    if (i < n4) {
        float4 v = in[i];
        ushort4 o;
        o.x = f2bf(v.x); o.y = f2bf(v.y); o.z = f2bf(v.z); o.w = f2bf(v.w);
        out[i] = o;
    }
}

// Register 4x4 transpose+cvt: in fp32 [z][R][Cc] -> out bf16 [z][Cc][R].
// 16B coalesced loads; 8B stores (L2 merges same-tile neighbors into full sectors).
__global__ void transpose_cvt_kernel(const float* __restrict__ in0, const float* __restrict__ in1,
                                     unsigned short* __restrict__ out0, unsigned short* __restrict__ out1,
                                     int R, int Cc, int zsplit) {
    int z = blockIdx.z;
    const float* in = (z < zsplit) ? in0 : in1;
    unsigned short* out = (z < zsplit) ? out0 : out1;
    int zz = (z < zsplit) ? z : z - zsplit;
    const size_t bs = (size_t)R * Cc;
    in += zz * bs; out += zz * bs;

    int tid = threadIdx.x;
    int cb = tid & 15, rb = tid >> 4;
    int r = blockIdx.y * 64 + rb * 4;
    int c = blockIdx.x * 64 + cb * 4;

    float4 v0 = *(const float4*)(in + (size_t)(r + 0) * Cc + c);
    float4 v1 = *(const float4*)(in + (size_t)(r + 1) * Cc + c);
    float4 v2 = *(const float4*)(in + (size_t)(r + 2) * Cc + c);
    float4 v3 = *(const float4*)(in + (size_t)(r + 3) * Cc + c);
    ushort4 o;
    o.x = f2bf(v0.x); o.y = f2bf(v1.x); o.z = f2bf(v2.x); o.w = f2bf(v3.x);
    *(ushort4*)(out + (size_t)(c + 0) * R + r) = o;
    o.x = f2bf(v0.y); o.y = f2bf(v1.y); o.z = f2bf(v2.y); o.w = f2bf(v3.y);
    *(ushort4*)(out + (size_t)(c + 1) * R + r) = o;
    o.x = f2bf(v0.z); o.y = f2bf(v1.z); o.z = f2bf(v2.z); o.w = f2bf(v3.z);
    *(ushort4*)(out + (size_t)(c + 2) * R + r) = o;
    o.x = f2bf(v0.w); o.y = f2bf(v1.w); o.z = f2bf(v2.w); o.w = f2bf(v3.w);
    *(ushort4*)(out + (size_t)(c + 3) * R + r) = o;
}

// ---------------- router ----------------
__global__ void router_kernel(const float* __restrict__ x, const float* __restrict__ Wg,
                              int* __restrict__ idxK, float* __restrict__ probK,
                              int* __restrict__ meta) {
    int t = blockIdx.x;
    int lane = threadIdx.x;
    const float* xr = x + (size_t)t * CDIM;
    float acc[NEXP];
#pragma unroll
    for (int e = 0; e < NEXP; e++) acc[e] = 0.f;
    for (int c = lane; c < CDIM; c += 64) {
        float xv = xr[c];
        const float* wr = Wg + c * NEXP;
#pragma unroll
        for (int e = 0; e < NEXP; e++) acc[e] += xv * wr[e];
    }
#pragma unroll
    for (int e = 0; e < NEXP; e++)
        for (int off = 32; off > 0; off >>= 1)
            acc[e] += __shfl_down(acc[e], off, 64);
    if (lane == 0) {
        int b0 = 0; float v0 = acc[0];
#pragma unroll
        for (int e = 1; e < NEXP; e++) if (acc[e] > v0) { v0 = acc[e]; b0 = e; }
        int b1 = -1; float v1 = -1e30f;
#pragma unroll
        for (int e = 0; e < NEXP; e++) if (e != b0 && acc[e] > v1) { v1 = acc[e]; b1 = e; }
        float p0 = 1.f / (1.f + __expf(v1 - v0));
        idxK[2 * t] = b0; idxK[2 * t + 1] = b1;
        probK[2 * t] = p0; probK[2 * t + 1] = 1.f - p0;
        atomicAdd(&meta[b0], 1);
        atomicAdd(&meta[b1], 1);
    }
}

// meta: [0..7] counts, [8..15] offsets, [16..23] cursor
__global__ void offsets_kernel(int* meta) {
    int s = 0;
    for (int e = 0; e < NEXP; e++) { meta[8 + e] = s; meta[16 + e] = s; s += meta[e]; }
}

__global__ void fill_kernel(const int* __restrict__ idxK, const float* __restrict__ probK,
                            int* __restrict__ meta, int* __restrict__ rowT, float* __restrict__ rowW) {
    int t = blockIdx.x * 256 + threadIdx.x;
    if (t >= NTOK) return;
#pragma unroll
    for (int k = 0; k < 2; k++) {
        int e = idxK[2 * t + k];
        int p = atomicAdd(&meta[16 + e], 1);
        rowT[p] = t;
        rowW[p] = probK[2 * t + k];
    }
}

// ---------------- merged fused gate GEMM: H = silu(A@W1) * (A@W2) ----------------
// z<8: expert (gathered rows, N=1408, grid.y covers 22 n-tiles).
// z=8/9: shared halves (N=2816, n0 = (z-8)*1408 + y*64).
// BM=128, BN=64, BK=32, double-buffered LDS (2x16KB), single barrier per step:
// prefetch k+1 issued before compute of k -> full compute phase of load flight.
// Swizzle: 64B rows, chunk' = chunk ^ ((row>>1)&3) -> max 2-way (free).
__global__ __launch_bounds__(256) void gemm12_kernel(
    const unsigned short* __restrict__ xb,
    const unsigned short* __restrict__ w1, const unsigned short* __restrict__ w2,
    const unsigned short* __restrict__ ws1, const unsigned short* __restrict__ ws2,
    unsigned short* __restrict__ hE, unsigned short* __restrict__ hS,
    const int* __restrict__ rowT, const int* __restrict__ meta) {
    const int z = blockIdx.z;
    const bool SH = (z >= 8);
    const int n0 = SH ? (z - 8) * 1408 + blockIdx.y * 64 : blockIdx.y * 64;
    const int M = SH ? NTOK : meta[z];
    const int base = SH ? 0 : meta[8 + z];
    const int m0 = blockIdx.x * 128;
    if (m0 >= M) return;

    const unsigned short* B1 = SH ? ws1 : w1 + (size_t)z * HDIM * CDIM;
    const unsigned short* B2 = SH ? ws2 : w2 + (size_t)z * HDIM * CDIM;

    // [As0|As1|B1_0|B1_1|B2_0|B2_1] in shorts: 4096,4096,2048,2048,2048,2048
    __shared__ unsigned short L[16384];  // 32 KB

    const int tid = threadIdx.x;
    const int srow = tid >> 2;             // 0..63
    const int key = (tid >> 3) & 3;        // = (row>>1)&3 for both A halves
    const int co = ((tid & 3) ^ key) << 3; // global chunk offset (shorts)

    int am0 = m0 + srow;       am0 = am0 < M ? am0 : M - 1;
    int am1 = m0 + 64 + srow;  am1 = am1 < M ? am1 : M - 1;
    long ar0 = SH ? am0 : rowT[base + am0];
    long ar1 = SH ? am1 : rowT[base + am1];
    const unsigned short* a0p = xb + (size_t)ar0 * CDIM + co;
    const unsigned short* a1p = xb + (size_t)ar1 * CDIM + co;
    const unsigned short* b1p = B1 + (size_t)(n0 + srow) * CDIM + co;
    const unsigned short* b2p = B2 + (size_t)(n0 + srow) * CDIM + co;

    const int w = tid >> 6, lane = tid & 63;
    const int wm = (w >> 1) * 64, wn = (w & 1) * 32;
    const int quad = lane >> 4, l15 = lane & 15;
    const int rcx = (quad ^ ((l15 >> 1) & 3)) << 3;  // fragment chunk (shorts)

    f4v acc1[4][2], acc2[4][2];
#pragma unroll
    for (int i = 0; i < 4; i++)
#pragma unroll
        for (int j = 0; j < 2; j++) {
            f4v zz = {0.f, 0.f, 0.f, 0.f};
            acc1[i][j] = zz; acc2[i][j] = zz;
        }

    auto issue = [&](int b, int k0) {
        g2l16(L + b * 4096 + tid * 8, a0p + k0);
        g2l16(L + b * 4096 + 2048 + tid * 8, a1p + k0);
        g2l16(L + 8192 + b * 2048 + tid * 8, b1p + k0);
        g2l16(L + 12288 + b * 2048 + tid * 8, b2p + k0);
    };

    issue(0, 0);
    __syncthreads();
#pragma unroll 1
    for (int ks = 0; ks < CDIM / 32; ks++) {
        if (ks + 1 < CDIM / 32) issue((ks + 1) & 1, (ks + 1) * 32);
        const unsigned short* Ab = L + (ks & 1) * 4096;
        const unsigned short* B1b = L + 8192 + (ks & 1) * 2048;
        const unsigned short* B2b = L + 12288 + (ks & 1) * 2048;
        s8v af[4], bf1[2], bf2[2];
#pragma unroll
        for (int mt = 0; mt < 4; mt++)
            af[mt] = *(const s8v*)(Ab + (wm + mt * 16 + l15) * 32 + rcx);
#pragma unroll
        for (int nt = 0; nt < 2; nt++) {
            bf1[nt] = *(const s8v*)(B1b + (wn + nt * 16 + l15) * 32 + rcx);
            bf2[nt] = *(const s8v*)(B2b + (wn + nt * 16 + l15) * 32 + rcx);
        }
#pragma unroll
        for (int mt = 0; mt < 4; mt++)
#pragma unroll
            for (int nt = 0; nt < 2; nt++) {
                acc1[mt][nt] = __builtin_amdgcn_mfma_f32_16x16x32_bf16(af[mt], bf1[nt], acc1[mt][nt], 0, 0, 0);
                acc2[mt][nt] = __builtin_amdgcn_mfma_f32_16x16x32_bf16(af[mt], bf2[nt], acc2[mt][nt], 0, 0, 0);
            }
        __syncthreads();
    }

#pragma unroll
    for (int mt = 0; mt < 4; mt++) {
#pragma unroll
        for (int r = 0; r < 4; r++) {
            int gm = m0 + wm + mt * 16 + quad * 4 + r;
            if (gm < M) {
                unsigned short* hrow = SH ? hS + (size_t)gm * HSDIM
                                          : hE + (size_t)(base + gm) * HDIM;
#pragma unroll
                for (int nt = 0; nt < 2; nt++) {
                    float z1 = acc1[mt][nt][r];
                    float z2 = acc2[mt][nt][r];
                    float hv = (z1 / (1.f + __expf(-z1))) * z2;
                    hrow[n0 + wn + nt * 16 + l15] = f2bf(hv);
                }
            }
        }
    }
}

// ---------------- merged down-proj GEMM: Out += w * (H @ W3) ----------------
// z<8: expert (A=hE, K=1408). z==8: shared (A=hS, K=2816). All-atomic epilogue.
// BM=128, BN=128, BK=32, same double-buffer structure (2x16KB).
__global__ __launch_bounds__(256) void gemm3_kernel(
    const unsigned short* __restrict__ hE, const unsigned short* __restrict__ hS,
    const unsigned short* __restrict__ w3, const unsigned short* __restrict__ ws3,
    float* __restrict__ Out,
    const int* __restrict__ rowT, const float* __restrict__ rowW, const int* __restrict__ meta) {
    const int z = blockIdx.z;
    const bool SH = (z == 8);
    const int M = SH ? NTOK : meta[z];
    const int base = SH ? 0 : meta[8 + z];
    const int m0 = blockIdx.x * 128;
    if (m0 >= M) return;
    const int n0 = blockIdx.y * 128;
    const int K = SH ? HSDIM : HDIM;
    const unsigned short* A = SH ? hS : hE;
    const unsigned short* B = SH ? ws3 : w3 + (size_t)z * CDIM * HDIM;

    // [As0|As1|Bs0|Bs1] in shorts: 4096 each
    __shared__ unsigned short L[16384];  // 32 KB

    const int tid = threadIdx.x;
    const int srow = tid >> 2;
    const int key = (tid >> 3) & 3;
    const int co = ((tid & 3) ^ key) << 3;

    int am0 = m0 + srow;       am0 = am0 < M ? am0 : M - 1;
    int am1 = m0 + 64 + srow;  am1 = am1 < M ? am1 : M - 1;
    const unsigned short* a0p = A + (size_t)(base + am0) * K + co;
    const unsigned short* a1p = A + (size_t)(base + am1) * K + co;
    const unsigned short* b0p = B + (size_t)(n0 + srow) * K + co;
    const unsigned short* b1p = B + (size_t)(n0 + 64 + srow) * K + co;

    const int w = tid >> 6, lane = tid & 63;
    const int wm = (w >> 1) * 64, wn = (w & 1) * 64;
    const int quad = lane >> 4, l15 = lane & 15;
    const int rcx = (quad ^ ((l15 >> 1) & 3)) << 3;

    f4v acc[4][4];
#pragma unroll
    for (int i = 0; i < 4; i++)
#pragma unroll
        for (int j = 0; j < 4; j++) {
            f4v zz = {0.f, 0.f, 0.f, 0.f};
            acc[i][j] = zz;
        }

    auto issue = [&](int b, int k0) {
        g2l16(L + b * 4096 + tid * 8, a0p + k0);
        g2l16(L + b * 4096 + 2048 + tid * 8, a1p + k0);
        g2l16(L + 8192 + b * 4096 + tid * 8, b0p + k0);
        g2l16(L + 8192 + b * 4096 + 2048 + tid * 8, b1p + k0);
    };

    const int NS = K / 32;
    issue(0, 0);
    __syncthreads();
#pragma unroll 1
    for (int ks = 0; ks < NS; ks++) {
        if (ks + 1 < NS) issue((ks + 1) & 1, (ks + 1) * 32);
        const unsigned short* Ab = L + (ks & 1) * 4096;
        const unsigned short* Bb = L + 8192 + (ks & 1) * 4096;
        s8v af[4], bf[4];
#pragma unroll
        for (int mt = 0; mt < 4; mt++)
            af[mt] = *(const s8v*)(Ab + (wm + mt * 16 + l15) * 32 + rcx);
#pragma unroll
        for (int nt = 0; nt < 4; nt++)
            bf[nt] = *(const s8v*)(Bb + (wn + nt * 16 + l15) * 32 + rcx);
#pragma unroll
        for (int mt = 0; mt < 4; mt++)
#pragma unroll
            for (int nt = 0; nt < 4; nt++)
                acc[mt][nt] = __builtin_amdgcn_mfma_f32_16x16x32_bf16(af[mt], bf[nt], acc[mt][nt], 0, 0, 0);
        __syncthreads();
    }

#pragma unroll
    for (int mt = 0; mt < 4; mt++) {
#pragma unroll
        for (int r = 0; r < 4; r++) {
            int gm = m0 + wm + mt * 16 + quad * 4 + r;
            if (gm < M) {
                int t; float wgt;
                if (SH) { t = gm; wgt = 1.f; }
                else    { int rr = base + gm; t = rowT[rr]; wgt = rowW[rr]; }
                size_t o = (size_t)t * CDIM + n0 + wn + l15;
#pragma unroll
                for (int nt = 0; nt < 4; nt++)
                    atomicAdd(&Out[o + nt * 16], wgt * acc[mt][nt][r]);
            }
        }
    }
}

// ---------------- launch ----------------

extern "C" void kernel_launch(void* const* d_in, const int* in_sizes, int n_in,
                              void* d_out, int out_size, void* d_ws, size_t ws_size,
                              hipStream_t stream) {
    const float* x   = (const float*)d_in[0];
    const float* Wg  = (const float*)d_in[1];
    const float* W1  = (const float*)d_in[2];
    const float* W2  = (const float*)d_in[3];
    const float* W3  = (const float*)d_in[4];
    const float* Ws1 = (const float*)d_in[5];
    const float* Ws2 = (const float*)d_in[6];
    const float* Ws3 = (const float*)d_in[7];
    float* out = (float*)d_out;

    char* p = (char*)d_ws;
    auto carve = [&](size_t bytes) {
        char* r = p;
        p += (bytes + 255) & ~(size_t)255;
        return r;
    };
    unsigned short* xb   = (unsigned short*)carve((size_t)NTOK * CDIM * 2);
    unsigned short* w1t  = (unsigned short*)carve((size_t)NEXP * HDIM * CDIM * 2);
    unsigned short* w2t  = (unsigned short*)carve((size_t)NEXP * HDIM * CDIM * 2);
    unsigned short* w3t  = (unsigned short*)carve((size_t)NEXP * CDIM * HDIM * 2);
    unsigned short* ws1t = (unsigned short*)carve((size_t)HSDIM * CDIM * 2);
    unsigned short* ws2t = (unsigned short*)carve((size_t)HSDIM * CDIM * 2);
    unsigned short* ws3t = (unsigned short*)carve((size_t)CDIM * HSDIM * 2);
    unsigned short* hE   = (unsigned short*)carve((size_t)2 * NTOK * HDIM * 2);
    unsigned short* hS   = (unsigned short*)carve((size_t)NTOK * HSDIM * 2);
    int*   idxK  = (int*)carve((size_t)NTOK * 2 * 4);
    float* probK = (float*)carve((size_t)NTOK * 2 * 4);
    int*   rowT  = (int*)carve((size_t)2 * NTOK * 4);
    float* rowW  = (float*)carve((size_t)2 * NTOK * 4);
    int*   meta  = (int*)carve(256);

    hipMemsetAsync(out, 0, (size_t)out_size * 4, stream);

    cvt_bf16_kernel<<<(NTOK * CDIM / 4 + 255) / 256, 256, 0, stream>>>(
        (const float4*)x, (ushort4*)xb, NTOK * CDIM / 4);
    // W1+W2: [8][1024][1408] -> [8][1408][1024]
    transpose_cvt_kernel<<<dim3(HDIM / 64, CDIM / 64, 16), 256, 0, stream>>>(
        W1, W2, w1t, w2t, CDIM, HDIM, 8);
    // W3: [8][1408][1024] -> [8][1024][1408]
    transpose_cvt_kernel<<<dim3(CDIM / 64, HDIM / 64, 8), 256, 0, stream>>>(
        W3, W3, w3t, w3t, HDIM, CDIM, 8);
    // Ws1+Ws2: [1024][2816] -> [2816][1024]
    transpose_cvt_kernel<<<dim3(HSDIM / 64, CDIM / 64, 2), 256, 0, stream>>>(
        Ws1, Ws2, ws1t, ws2t, CDIM, HSDIM, 1);
    // Ws3: [2816][1024] -> [1024][2816]
    transpose_cvt_kernel<<<dim3(CDIM / 64, HSDIM / 64, 1), 256, 0, stream>>>(
        Ws3, Ws3, ws3t, ws3t, HSDIM, CDIM, 1);

    hipMemsetAsync(meta, 0, 256, stream);
    router_kernel<<<NTOK, 64, 0, stream>>>(x, Wg, idxK, probK, meta);
    offsets_kernel<<<1, 1, 0, stream>>>(meta);
    fill_kernel<<<NTOK / 256, 256, 0, stream>>>(idxK, probK, meta, rowT, rowW);

    // merged up-proj: z 0..7 experts (22 n-tiles), z 8..9 shared halves
    gemm12_kernel<<<dim3(NTOK / 128, HDIM / 64, 10), 256, 0, stream>>>(
        xb, w1t, w2t, ws1t, ws2t, hE, hS, rowT, meta);
    // merged down-proj (all atomic onto zeroed out)
    gemm3_kernel<<<dim3(NTOK / 128, CDIM / 128, 9), 256, 0, stream>>>(
        hE, hS, w3t, ws3t, out, rowT, rowW, meta);
}

// Round 5
// 969.827 us; speedup vs baseline: 1.3896x; 1.0510x over previous
//
#include <hip/hip_runtime.h>
#include <cstdint>

#define NTOK 8192
#define CDIM 1024
#define HDIM 1408
#define HSDIM 2816
#define NEXP 8

typedef __attribute__((ext_vector_type(8))) short s8v;
typedef __attribute__((ext_vector_type(4))) float f4v;

__device__ __forceinline__ unsigned short f2bf(float f) {
    unsigned int u = __float_as_uint(f);
    unsigned int r = (u + 0x7fffu + ((u >> 16) & 1u)) >> 16;  // RNE
    return (unsigned short)r;
}

// ---------------- conversion kernels ----------------

__global__ void cvt_bf16_kernel(const float4* __restrict__ in, ushort4* __restrict__ out, int n4) {
    int i = blockIdx.x * blockDim.x + threadIdx.x;
    if (i < n4) {
        float4 v = in[i];
        ushort4 o;
        o.x = f2bf(v.x); o.y = f2bf(v.y); o.z = f2bf(v.z); o.w = f2bf(v.w);
        out[i] = o;
    }
}

// Register 4x4 transpose+cvt: in fp32 [z][R][Cc] -> out bf16 [z][Cc][R].
__global__ void transpose_cvt_kernel(const float* __restrict__ in0, const float* __restrict__ in1,
                                     unsigned short* __restrict__ out0, unsigned short* __restrict__ out1,
                                     int R, int Cc, int zsplit) {
    int z = blockIdx.z;
    const float* in = (z < zsplit) ? in0 : in1;
    unsigned short* out = (z < zsplit) ? out0 : out1;
    int zz = (z < zsplit) ? z : z - zsplit;
    const size_t bs = (size_t)R * Cc;
    in += zz * bs; out += zz * bs;

    int tid = threadIdx.x;
    int cb = tid & 15, rb = tid >> 4;
    int r = blockIdx.y * 64 + rb * 4;
    int c = blockIdx.x * 64 + cb * 4;

    float4 v0 = *(const float4*)(in + (size_t)(r + 0) * Cc + c);
    float4 v1 = *(const float4*)(in + (size_t)(r + 1) * Cc + c);
    float4 v2 = *(const float4*)(in + (size_t)(r + 2) * Cc + c);
    float4 v3 = *(const float4*)(in + (size_t)(r + 3) * Cc + c);
    ushort4 o;
    o.x = f2bf(v0.x); o.y = f2bf(v1.x); o.z = f2bf(v2.x); o.w = f2bf(v3.x);
    *(ushort4*)(out + (size_t)(c + 0) * R + r) = o;
    o.x = f2bf(v0.y); o.y = f2bf(v1.y); o.z = f2bf(v2.y); o.w = f2bf(v3.y);
    *(ushort4*)(out + (size_t)(c + 1) * R + r) = o;
    o.x = f2bf(v0.z); o.y = f2bf(v1.z); o.z = f2bf(v2.z); o.w = f2bf(v3.z);
    *(ushort4*)(out + (size_t)(c + 2) * R + r) = o;
    o.x = f2bf(v0.w); o.y = f2bf(v1.w); o.z = f2bf(v2.w); o.w = f2bf(v3.w);
    *(ushort4*)(out + (size_t)(c + 3) * R + r) = o;
}

// ---------------- router ----------------
__global__ void router_kernel(const float* __restrict__ x, const float* __restrict__ Wg,
                              int* __restrict__ idxK, float* __restrict__ probK,
                              int* __restrict__ meta) {
    int t = blockIdx.x;
    int lane = threadIdx.x;
    const float* xr = x + (size_t)t * CDIM;
    float acc[NEXP];
#pragma unroll
    for (int e = 0; e < NEXP; e++) acc[e] = 0.f;
    for (int c = lane; c < CDIM; c += 64) {
        float xv = xr[c];
        const float* wr = Wg + c * NEXP;
#pragma unroll
        for (int e = 0; e < NEXP; e++) acc[e] += xv * wr[e];
    }
#pragma unroll
    for (int e = 0; e < NEXP; e++)
        for (int off = 32; off > 0; off >>= 1)
            acc[e] += __shfl_down(acc[e], off, 64);
    if (lane == 0) {
        int b0 = 0; float v0 = acc[0];
#pragma unroll
        for (int e = 1; e < NEXP; e++) if (acc[e] > v0) { v0 = acc[e]; b0 = e; }
        int b1 = -1; float v1 = -1e30f;
#pragma unroll
        for (int e = 0; e < NEXP; e++) if (e != b0 && acc[e] > v1) { v1 = acc[e]; b1 = e; }
        float p0 = 1.f / (1.f + __expf(v1 - v0));
        idxK[2 * t] = b0; idxK[2 * t + 1] = b1;
        probK[2 * t] = p0; probK[2 * t + 1] = 1.f - p0;
        atomicAdd(&meta[b0], 1);
        atomicAdd(&meta[b1], 1);
    }
}

// meta: [0..7] counts, [8..15] offsets, [16..23] cursor
__global__ void offsets_kernel(int* meta) {
    int s = 0;
    for (int e = 0; e < NEXP; e++) { meta[8 + e] = s; meta[16 + e] = s; s += meta[e]; }
}

__global__ void fill_kernel(const int* __restrict__ idxK, const float* __restrict__ probK,
                            int* __restrict__ meta, int* __restrict__ rowT, float* __restrict__ rowW) {
    int t = blockIdx.x * 256 + threadIdx.x;
    if (t >= NTOK) return;
#pragma unroll
    for (int k = 0; k < 2; k++) {
        int e = idxK[2 * t + k];
        int p = atomicAdd(&meta[16 + e], 1);
        rowT[p] = t;
        rowW[p] = probK[2 * t + k];
    }
}

// ---------------- merged fused gate GEMM: H = silu(A@W1) * (A@W2) ----------------
// 1D grid, XCD-pinned: ids [0,3520): experts, id%8==z (20 x-slots x 22 y-tiles);
// ids [3520,6336): shared, x-fastest (x%8 -> stable XCD per A-tile).
// BM=128, BN=64, BK=32. Depth-2 VGPR prefetch + ds_write staging: NO global_load_lds,
// so barriers don't drain vmcnt -> each load gets a full K-step in flight.
__global__ __launch_bounds__(256) void gemm12_kernel(
    const unsigned short* __restrict__ xb,
    const unsigned short* __restrict__ w1, const unsigned short* __restrict__ w2,
    const unsigned short* __restrict__ ws1, const unsigned short* __restrict__ ws2,
    unsigned short* __restrict__ hE, unsigned short* __restrict__ hS,
    const int* __restrict__ rowT, const int* __restrict__ meta) {
    const int id = blockIdx.x;
    int z, m0, n0; bool SH;
    if (id < 3520) { SH = false; z = id & 7; int q = id >> 3; m0 = (q % 20) * 128; n0 = (q / 20) * 64; }
    else           { SH = true;  z = 8; int q = id - 3520; m0 = (q & 63) * 128; n0 = (q >> 6) * 64; }
    const int M = SH ? NTOK : meta[z];
    const int base = SH ? 0 : meta[8 + z];
    if (m0 >= M) return;

    const unsigned short* B1 = SH ? ws1 : w1 + (size_t)z * HDIM * CDIM;
    const unsigned short* B2 = SH ? ws2 : w2 + (size_t)z * HDIM * CDIM;

    // [A0|A1 | B1_0|B1_1 | B2_0|B2_1] shorts: 4096x2, 2048x2, 2048x2 (32 KB)
    __shared__ unsigned short L[16384];

    const int tid = threadIdx.x;
    const int srow = tid >> 2;             // 0..63
    const int key = (tid >> 3) & 3;        // (row>>1)&3
    const int co = ((tid & 3) ^ key) << 3; // swizzled chunk (shorts)

    int am0 = m0 + srow;       am0 = am0 < M ? am0 : M - 1;
    int am1 = m0 + 64 + srow;  am1 = am1 < M ? am1 : M - 1;
    long ar0 = SH ? am0 : rowT[base + am0];
    long ar1 = SH ? am1 : rowT[base + am1];
    const unsigned short* a0p = xb + (size_t)ar0 * CDIM + co;
    const unsigned short* a1p = xb + (size_t)ar1 * CDIM + co;
    const unsigned short* b1p = B1 + (size_t)(n0 + srow) * CDIM + co;
    const unsigned short* b2p = B2 + (size_t)(n0 + srow) * CDIM + co;

    const int w = tid >> 6, lane = tid & 63;
    const int wm = (w >> 1) * 64, wn = (w & 1) * 32;
    const int quad = lane >> 4, l15 = lane & 15;
    const int rcx = (quad ^ ((l15 >> 1) & 3)) << 3;

    f4v acc1[4][2], acc2[4][2];
#pragma unroll
    for (int i = 0; i < 4; i++)
#pragma unroll
        for (int j = 0; j < 2; j++) {
            f4v zz = {0.f, 0.f, 0.f, 0.f};
            acc1[i][j] = zz; acc2[i][j] = zz;
        }

    uint4 r0a0, r0a1, r0b1, r0b2;  // set 0
    uint4 r1a0, r1a1, r1b1, r1b2;  // set 1

#define LOADSET12(s, k0) do { \
        r##s##a0 = *(const uint4*)(a0p + (k0)); \
        r##s##a1 = *(const uint4*)(a1p + (k0)); \
        r##s##b1 = *(const uint4*)(b1p + (k0)); \
        r##s##b2 = *(const uint4*)(b2p + (k0)); } while (0)
#define WRITESET12(b, s) do { \
        *(uint4*)(L + (b) * 4096 + tid * 8) = r##s##a0; \
        *(uint4*)(L + (b) * 4096 + 2048 + tid * 8) = r##s##a1; \
        *(uint4*)(L + 8192 + (b) * 2048 + tid * 8) = r##s##b1; \
        *(uint4*)(L + 12288 + (b) * 2048 + tid * 8) = r##s##b2; } while (0)

    auto compute = [&](int b) {
        const unsigned short* Ab = L + b * 4096;
        const unsigned short* B1b = L + 8192 + b * 2048;
        const unsigned short* B2b = L + 12288 + b * 2048;
        s8v af[4], bf1[2], bf2[2];
#pragma unroll
        for (int mt = 0; mt < 4; mt++)
            af[mt] = *(const s8v*)(Ab + (wm + mt * 16 + l15) * 32 + rcx);
#pragma unroll
        for (int nt = 0; nt < 2; nt++) {
            bf1[nt] = *(const s8v*)(B1b + (wn + nt * 16 + l15) * 32 + rcx);
            bf2[nt] = *(const s8v*)(B2b + (wn + nt * 16 + l15) * 32 + rcx);
        }
#pragma unroll
        for (int mt = 0; mt < 4; mt++)
#pragma unroll
            for (int nt = 0; nt < 2; nt++) {
                acc1[mt][nt] = __builtin_amdgcn_mfma_f32_16x16x32_bf16(af[mt], bf1[nt], acc1[mt][nt], 0, 0, 0);
                acc2[mt][nt] = __builtin_amdgcn_mfma_f32_16x16x32_bf16(af[mt], bf2[nt], acc2[mt][nt], 0, 0, 0);
            }
    };

    const int NS = CDIM / 32;  // 32, even
    LOADSET12(0, 0);
    LOADSET12(1, 32);
    WRITESET12(0, 0);
    __syncthreads();
#pragma unroll 1
    for (int ks = 0; ks < NS; ks += 2) {
        if (ks + 2 < NS) LOADSET12(0, (ks + 2) * 32);
        WRITESET12(1, 1);        // data ks+1 -> lds1 (vmcnt waits only set1)
        compute(0);              // data ks
        __syncthreads();
        if (ks + 3 < NS) LOADSET12(1, (ks + 3) * 32);
        compute(1);              // data ks+1
        WRITESET12(0, 0);        // data ks+2 -> lds0 (garbage on last iter, unread)
        __syncthreads();
    }
#undef LOADSET12
#undef WRITESET12

#pragma unroll
    for (int mt = 0; mt < 4; mt++) {
#pragma unroll
        for (int r = 0; r < 4; r++) {
            int gm = m0 + wm + mt * 16 + quad * 4 + r;
            if (gm < M) {
                unsigned short* hrow = SH ? hS + (size_t)gm * HSDIM
                                          : hE + (size_t)(base + gm) * HDIM;
#pragma unroll
                for (int nt = 0; nt < 2; nt++) {
                    float z1 = acc1[mt][nt][r];
                    float z2 = acc2[mt][nt][r];
                    float hv = (z1 / (1.f + __expf(-z1))) * z2;
                    hrow[n0 + wn + nt * 16 + l15] = f2bf(hv);
                }
            }
        }
    }
}

// ---------------- merged down-proj GEMM: Out += w * (H @ W3) ----------------
// 1D grid: ids [0,1280): experts id%8==z (20 x-slots x 8 n-tiles);
// ids [1280,1792): shared. BM=128, BN=128, BK=32, same depth-2 VGPR pipeline.
__global__ __launch_bounds__(256) void gemm3_kernel(
    const unsigned short* __restrict__ hE, const unsigned short* __restrict__ hS,
    const unsigned short* __restrict__ w3, const unsigned short* __restrict__ ws3,
    float* __restrict__ Out,
    const int* __restrict__ rowT, const float* __restrict__ rowW, const int* __restrict__ meta) {
    const int id = blockIdx.x;
    int z, m0, n0; bool SH;
    if (id < 1280) { SH = false; z = id & 7; int q = id >> 3; m0 = (q % 20) * 128; n0 = (q / 20) * 128; }
    else           { SH = true;  z = 8; int q = id - 1280; m0 = (q & 63) * 128; n0 = (q >> 6) * 128; }
    const int M = SH ? NTOK : meta[z];
    const int base = SH ? 0 : meta[8 + z];
    if (m0 >= M) return;
    const int K = SH ? HSDIM : HDIM;
    const unsigned short* A = SH ? hS : hE;
    const unsigned short* B = SH ? ws3 : w3 + (size_t)z * CDIM * HDIM;

    // [A0|A1 | B0|B1] shorts: 4096x2, 4096x2 (32 KB)
    __shared__ unsigned short L[16384];

    const int tid = threadIdx.x;
    const int srow = tid >> 2;
    const int key = (tid >> 3) & 3;
    const int co = ((tid & 3) ^ key) << 3;

    int am0 = m0 + srow;       am0 = am0 < M ? am0 : M - 1;
    int am1 = m0 + 64 + srow;  am1 = am1 < M ? am1 : M - 1;
    const unsigned short* a0p = A + (size_t)(base + am0) * K + co;
    const unsigned short* a1p = A + (size_t)(base + am1) * K + co;
    const unsigned short* b0p = B + (size_t)(n0 + srow) * K + co;
    const unsigned short* b1p = B + (size_t)(n0 + 64 + srow) * K + co;

    const int w = tid >> 6, lane = tid & 63;
    const int wm = (w >> 1) * 64, wn = (w & 1) * 64;
    const int quad = lane >> 4, l15 = lane & 15;
    const int rcx = (quad ^ ((l15 >> 1) & 3)) << 3;

    f4v acc[4][4];
#pragma unroll
    for (int i = 0; i < 4; i++)
#pragma unroll
        for (int j = 0; j < 4; j++) {
            f4v zz = {0.f, 0.f, 0.f, 0.f};
            acc[i][j] = zz;
        }

    uint4 r0a0, r0a1, r0b0, r0b1;
    uint4 r1a0, r1a1, r1b0, r1b1;

#define LOADSET3(s, k0) do { \
        r##s##a0 = *(const uint4*)(a0p + (k0)); \
        r##s##a1 = *(const uint4*)(a1p + (k0)); \
        r##s##b0 = *(const uint4*)(b0p + (k0)); \
        r##s##b1 = *(const uint4*)(b1p + (k0)); } while (0)
#define WRITESET3(b, s) do { \
        *(uint4*)(L + (b) * 4096 + tid * 8) = r##s##a0; \
        *(uint4*)(L + (b) * 4096 + 2048 + tid * 8) = r##s##a1; \
        *(uint4*)(L + 8192 + (b) * 4096 + tid * 8) = r##s##b0; \
        *(uint4*)(L + 8192 + (b) * 4096 + 2048 + tid * 8) = r##s##b1; } while (0)

    auto compute = [&](int b) {
        const unsigned short* Ab = L + b * 4096;
        const unsigned short* Bb = L + 8192 + b * 4096;
        s8v af[4], bf[4];
#pragma unroll
        for (int mt = 0; mt < 4; mt++)
            af[mt] = *(const s8v*)(Ab + (wm + mt * 16 + l15) * 32 + rcx);
#pragma unroll
        for (int nt = 0; nt < 4; nt++)
            bf[nt] = *(const s8v*)(Bb + (wn + nt * 16 + l15) * 32 + rcx);
#pragma unroll
        for (int mt = 0; mt < 4; mt++)
#pragma unroll
            for (int nt = 0; nt < 4; nt++)
                acc[mt][nt] = __builtin_amdgcn_mfma_f32_16x16x32_bf16(af[mt], bf[nt], acc[mt][nt], 0, 0, 0);
    };

    const int NS = K / 32;  // 44 or 88, even
    LOADSET3(0, 0);
    LOADSET3(1, 32);
    WRITESET3(0, 0);
    __syncthreads();
#pragma unroll 1
    for (int ks = 0; ks < NS; ks += 2) {
        if (ks + 2 < NS) LOADSET3(0, (ks + 2) * 32);
        WRITESET3(1, 1);
        compute(0);
        __syncthreads();
        if (ks + 3 < NS) LOADSET3(1, (ks + 3) * 32);
        compute(1);
        WRITESET3(0, 0);
        __syncthreads();
    }
#undef LOADSET3
#undef WRITESET3

#pragma unroll
    for (int mt = 0; mt < 4; mt++) {
#pragma unroll
        for (int r = 0; r < 4; r++) {
            int gm = m0 + wm + mt * 16 + quad * 4 + r;
            if (gm < M) {
                int t; float wgt;
                if (SH) { t = gm; wgt = 1.f; }
                else    { int rr = base + gm; t = rowT[rr]; wgt = rowW[rr]; }
                size_t o = (size_t)t * CDIM + n0 + wn + l15;
#pragma unroll
                for (int nt = 0; nt < 4; nt++)
                    atomicAdd(&Out[o + nt * 16], wgt * acc[mt][nt][r]);
            }
        }
    }
}

// ---------------- launch ----------------

extern "C" void kernel_launch(void* const* d_in, const int* in_sizes, int n_in,
                              void* d_out, int out_size, void* d_ws, size_t ws_size,
                              hipStream_t stream) {
    const float* x   = (const float*)d_in[0];
    const float* Wg  = (const float*)d_in[1];
    const float* W1  = (const float*)d_in[2];
    const float* W2  = (const float*)d_in[3];
    const float* W3  = (const float*)d_in[4];
    const float* Ws1 = (const float*)d_in[5];
    const float* Ws2 = (const float*)d_in[6];
    const float* Ws3 = (const float*)d_in[7];
    float* out = (float*)d_out;

    char* p = (char*)d_ws;
    auto carve = [&](size_t bytes) {
        char* r = p;
        p += (bytes + 255) & ~(size_t)255;
        return r;
    };
    unsigned short* xb   = (unsigned short*)carve((size_t)NTOK * CDIM * 2);
    unsigned short* w1t  = (unsigned short*)carve((size_t)NEXP * HDIM * CDIM * 2);
    unsigned short* w2t  = (unsigned short*)carve((size_t)NEXP * HDIM * CDIM * 2);
    unsigned short* w3t  = (unsigned short*)carve((size_t)NEXP * CDIM * HDIM * 2);
    unsigned short* ws1t = (unsigned short*)carve((size_t)HSDIM * CDIM * 2);
    unsigned short* ws2t = (unsigned short*)carve((size_t)HSDIM * CDIM * 2);
    unsigned short* ws3t = (unsigned short*)carve((size_t)CDIM * HSDIM * 2);
    unsigned short* hE   = (unsigned short*)carve((size_t)2 * NTOK * HDIM * 2);
    unsigned short* hS   = (unsigned short*)carve((size_t)NTOK * HSDIM * 2);
    int*   idxK  = (int*)carve((size_t)NTOK * 2 * 4);
    float* probK = (float*)carve((size_t)NTOK * 2 * 4);
    int*   rowT  = (int*)carve((size_t)2 * NTOK * 4);
    float* rowW  = (float*)carve((size_t)2 * NTOK * 4);
    int*   meta  = (int*)carve(256);

    hipMemsetAsync(out, 0, (size_t)out_size * 4, stream);

    cvt_bf16_kernel<<<(NTOK * CDIM / 4 + 255) / 256, 256, 0, stream>>>(
        (const float4*)x, (ushort4*)xb, NTOK * CDIM / 4);
    transpose_cvt_kernel<<<dim3(HDIM / 64, CDIM / 64, 16), 256, 0, stream>>>(
        W1, W2, w1t, w2t, CDIM, HDIM, 8);
    transpose_cvt_kernel<<<dim3(CDIM / 64, HDIM / 64, 8), 256, 0, stream>>>(
        W3, W3, w3t, w3t, HDIM, CDIM, 8);
    transpose_cvt_kernel<<<dim3(HSDIM / 64, CDIM / 64, 2), 256, 0, stream>>>(
        Ws1, Ws2, ws1t, ws2t, CDIM, HSDIM, 1);
    transpose_cvt_kernel<<<dim3(CDIM / 64, HSDIM / 64, 1), 256, 0, stream>>>(
        Ws3, Ws3, ws3t, ws3t, HSDIM, CDIM, 1);

    hipMemsetAsync(meta, 0, 256, stream);
    router_kernel<<<NTOK, 64, 0, stream>>>(x, Wg, idxK, probK, meta);
    offsets_kernel<<<1, 1, 0, stream>>>(meta);
    fill_kernel<<<NTOK / 256, 256, 0, stream>>>(idxK, probK, meta, rowT, rowW);

    // up-proj: 8*20*22=3520 expert blocks (id%8=expert) + 44*64=2816 shared
    gemm12_kernel<<<3520 + 2816, 256, 0, stream>>>(
        xb, w1t, w2t, ws1t, ws2t, hE, hS, rowT, meta);
    // down-proj: 8*20*8=1280 expert blocks + 8*64=512 shared (all atomic)
    gemm3_kernel<<<1280 + 512, 256, 0, stream>>>(
        hE, hS, w3t, ws3t, out, rowT, rowW, meta);
}

// Round 6
// 965.588 us; speedup vs baseline: 1.3957x; 1.0044x over previous
//
#include <hip/hip_runtime.h>
#include <cstdint>

#define NTOK 8192
#define CDIM 1024
#define HDIM 1408
#define HSDIM 2816
#define NEXP 8

typedef __attribute__((ext_vector_type(8))) short s8v;
typedef __attribute__((ext_vector_type(4))) float f4v;
typedef __attribute__((ext_vector_type(8))) unsigned short u16x8;

__device__ __forceinline__ unsigned short f2bf(float f) {
    unsigned int u = __float_as_uint(f);
    unsigned int r = (u + 0x7fffu + ((u >> 16) & 1u)) >> 16;  // RNE
    return (unsigned short)r;
}

// ---------------- conversion kernels ----------------

__global__ void cvt_bf16_kernel(const float4* __restrict__ in, ushort4* __restrict__ out, int n4) {
    int i = blockIdx.x * blockDim.x + threadIdx.x;
    if (i < n4) {
        float4 v = in[i];
        ushort4 o;
        o.x = f2bf(v.x); o.y = f2bf(v.y); o.z = f2bf(v.z); o.w = f2bf(v.w);
        out[i] = o;
    }
}

// 64x64 LDS-staged transpose+cvt: fp32 [z][R][Cc] -> bf16 [z][Cc][R].
// Loads: float4, 4 lanes = 64B contiguous per input row.
// Stores: 2x 16B per thread, 4 lanes = 128B contiguous per output row.
__global__ __launch_bounds__(256) void transpose_cvt_kernel(
    const float* __restrict__ in0, const float* __restrict__ in1,
    unsigned short* __restrict__ out0, unsigned short* __restrict__ out1,
    int R, int Cc, int zsplit) {
    __shared__ float T[64][68];
    int z = blockIdx.z;
    const float* in = (z < zsplit) ? in0 : in1;
    unsigned short* out = (z < zsplit) ? out0 : out1;
    int zz = (z < zsplit) ? z : z - zsplit;
    const size_t bs = (size_t)R * Cc;
    in += zz * bs; out += zz * bs;

    const int t = threadIdx.x;
    const int r0 = blockIdx.y * 64, c0 = blockIdx.x * 64;

    // load phase: row rl, four float4 chunks
    {
        const int rl = t >> 2, cq = t & 3;
        const float* src = in + (size_t)(r0 + rl) * Cc + c0;
#pragma unroll
        for (int i = 0; i < 4; i++) {
            float4 v = *(const float4*)(src + (cq + 4 * i) * 4);
            *(float4*)&T[rl][(cq + 4 * i) * 4] = v;
        }
    }
    __syncthreads();
    // store phase: output row c = c0+cl, r-chunk rq*16..+15
    {
        const int cl = t >> 2, rq = t & 3;
        unsigned short* dst = out + (size_t)(c0 + cl) * R + r0 + rq * 16;
        u16x8 lo, hi;
#pragma unroll
        for (int j = 0; j < 8; j++) lo[j] = f2bf(T[rq * 16 + j][cl]);
#pragma unroll
        for (int j = 0; j < 8; j++) hi[j] = f2bf(T[rq * 16 + 8 + j][cl]);
        *(u16x8*)dst = lo;
        *(u16x8*)(dst + 8) = hi;
    }
}

// ---------------- router ----------------
__global__ void router_kernel(const float* __restrict__ x, const float* __restrict__ Wg,
                              int* __restrict__ idxK, float* __restrict__ probK,
                              int* __restrict__ meta) {
    int t = blockIdx.x;
    int lane = threadIdx.x;
    const float* xr = x + (size_t)t * CDIM;
    float acc[NEXP];
#pragma unroll
    for (int e = 0; e < NEXP; e++) acc[e] = 0.f;
    for (int c = lane; c < CDIM; c += 64) {
        float xv = xr[c];
        const float* wr = Wg + c * NEXP;
#pragma unroll
        for (int e = 0; e < NEXP; e++) acc[e] += xv * wr[e];
    }
#pragma unroll
    for (int e = 0; e < NEXP; e++)
        for (int off = 32; off > 0; off >>= 1)
            acc[e] += __shfl_down(acc[e], off, 64);
    if (lane == 0) {
        int b0 = 0; float v0 = acc[0];
#pragma unroll
        for (int e = 1; e < NEXP; e++) if (acc[e] > v0) { v0 = acc[e]; b0 = e; }
        int b1 = -1; float v1 = -1e30f;
#pragma unroll
        for (int e = 0; e < NEXP; e++) if (e != b0 && acc[e] > v1) { v1 = acc[e]; b1 = e; }
        float p0 = 1.f / (1.f + __expf(v1 - v0));
        idxK[2 * t] = b0; idxK[2 * t + 1] = b1;
        probK[2 * t] = p0; probK[2 * t + 1] = 1.f - p0;
        atomicAdd(&meta[b0], 1);
        atomicAdd(&meta[b1], 1);
    }
}

// meta: [0..7] counts, [8..15] offsets, [16..23] cursor
__global__ void offsets_kernel(int* meta) {
    int s = 0;
    for (int e = 0; e < NEXP; e++) { meta[8 + e] = s; meta[16 + e] = s; s += meta[e]; }
}

__global__ void fill_kernel(const int* __restrict__ idxK, const float* __restrict__ probK,
                            int* __restrict__ meta, int* __restrict__ rowT, float* __restrict__ rowW) {
    int t = blockIdx.x * 256 + threadIdx.x;
    if (t >= NTOK) return;
#pragma unroll
    for (int k = 0; k < 2; k++) {
        int e = idxK[2 * t + k];
        int p = atomicAdd(&meta[16 + e], 1);
        rowT[p] = t;
        rowW[p] = probK[2 * t + k];
    }
}

// ---------------- merged fused gate GEMM: H = silu(A@W1) * (A@W2) ----------------
// 1D grid, XCD-pinned: ids [0,3520): experts, id%8==z; ids [3520,6336): shared.
// BM=128, BN=64, BK=32. Depth-2 VGPR prefetch + ds_write staging (no vmcnt(0) at barriers).
__global__ __launch_bounds__(256) void gemm12_kernel(
    const unsigned short* __restrict__ xb,
    const unsigned short* __restrict__ w1, const unsigned short* __restrict__ w2,
    const unsigned short* __restrict__ ws1, const unsigned short* __restrict__ ws2,
    unsigned short* __restrict__ hE, unsigned short* __restrict__ hS,
    const int* __restrict__ rowT, const int* __restrict__ meta) {
    const int id = blockIdx.x;
    int z, m0, n0; bool SH;
    if (id < 3520) { SH = false; z = id & 7; int q = id >> 3; m0 = (q % 20) * 128; n0 = (q / 20) * 64; }
    else           { SH = true;  z = 8; int q = id - 3520; m0 = (q & 63) * 128; n0 = (q >> 6) * 64; }
    const int M = SH ? NTOK : meta[z];
    const int base = SH ? 0 : meta[8 + z];
    if (m0 >= M) return;

    const unsigned short* B1 = SH ? ws1 : w1 + (size_t)z * HDIM * CDIM;
    const unsigned short* B2 = SH ? ws2 : w2 + (size_t)z * HDIM * CDIM;

    __shared__ unsigned short L[16384];  // 32 KB

    const int tid = threadIdx.x;
    const int srow = tid >> 2;
    const int key = (tid >> 3) & 3;
    const int co = ((tid & 3) ^ key) << 3;

    int am0 = m0 + srow;       am0 = am0 < M ? am0 : M - 1;
    int am1 = m0 + 64 + srow;  am1 = am1 < M ? am1 : M - 1;
    long ar0 = SH ? am0 : rowT[base + am0];
    long ar1 = SH ? am1 : rowT[base + am1];
    const unsigned short* a0p = xb + (size_t)ar0 * CDIM + co;
    const unsigned short* a1p = xb + (size_t)ar1 * CDIM + co;
    const unsigned short* b1p = B1 + (size_t)(n0 + srow) * CDIM + co;
    const unsigned short* b2p = B2 + (size_t)(n0 + srow) * CDIM + co;

    const int w = tid >> 6, lane = tid & 63;
    const int wm = (w >> 1) * 64, wn = (w & 1) * 32;
    const int quad = lane >> 4, l15 = lane & 15;
    const int rcx = (quad ^ ((l15 >> 1) & 3)) << 3;

    f4v acc1[4][2], acc2[4][2];
#pragma unroll
    for (int i = 0; i < 4; i++)
#pragma unroll
        for (int j = 0; j < 2; j++) {
            f4v zz = {0.f, 0.f, 0.f, 0.f};
            acc1[i][j] = zz; acc2[i][j] = zz;
        }

    uint4 r0a0, r0a1, r0b1, r0b2;
    uint4 r1a0, r1a1, r1b1, r1b2;

#define LOADSET12(s, k0) do { \
        r##s##a0 = *(const uint4*)(a0p + (k0)); \
        r##s##a1 = *(const uint4*)(a1p + (k0)); \
        r##s##b1 = *(const uint4*)(b1p + (k0)); \
        r##s##b2 = *(const uint4*)(b2p + (k0)); } while (0)
#define WRITESET12(b, s) do { \
        *(uint4*)(L + (b) * 4096 + tid * 8) = r##s##a0; \
        *(uint4*)(L + (b) * 4096 + 2048 + tid * 8) = r##s##a1; \
        *(uint4*)(L + 8192 + (b) * 2048 + tid * 8) = r##s##b1; \
        *(uint4*)(L + 12288 + (b) * 2048 + tid * 8) = r##s##b2; } while (0)

    auto compute = [&](int b) {
        const unsigned short* Ab = L + b * 4096;
        const unsigned short* B1b = L + 8192 + b * 2048;
        const unsigned short* B2b = L + 12288 + b * 2048;
        s8v af[4], bf1[2], bf2[2];
#pragma unroll
        for (int mt = 0; mt < 4; mt++)
            af[mt] = *(const s8v*)(Ab + (wm + mt * 16 + l15) * 32 + rcx);
#pragma unroll
        for (int nt = 0; nt < 2; nt++) {
            bf1[nt] = *(const s8v*)(B1b + (wn + nt * 16 + l15) * 32 + rcx);
            bf2[nt] = *(const s8v*)(B2b + (wn + nt * 16 + l15) * 32 + rcx);
        }
#pragma unroll
        for (int mt = 0; mt < 4; mt++)
#pragma unroll
            for (int nt = 0; nt < 2; nt++) {
                acc1[mt][nt] = __builtin_amdgcn_mfma_f32_16x16x32_bf16(af[mt], bf1[nt], acc1[mt][nt], 0, 0, 0);
                acc2[mt][nt] = __builtin_amdgcn_mfma_f32_16x16x32_bf16(af[mt], bf2[nt], acc2[mt][nt], 0, 0, 0);
            }
    };

    const int NS = CDIM / 32;
    LOADSET12(0, 0);
    LOADSET12(1, 32);
    WRITESET12(0, 0);
    __syncthreads();
#pragma unroll 1
    for (int ks = 0; ks < NS; ks += 2) {
        if (ks + 2 < NS) LOADSET12(0, (ks + 2) * 32);
        WRITESET12(1, 1);
        compute(0);
        __syncthreads();
        if (ks + 3 < NS) LOADSET12(1, (ks + 3) * 32);
        compute(1);
        WRITESET12(0, 0);
        __syncthreads();
    }
#undef LOADSET12
#undef WRITESET12

#pragma unroll
    for (int mt = 0; mt < 4; mt++) {
#pragma unroll
        for (int r = 0; r < 4; r++) {
            int gm = m0 + wm + mt * 16 + quad * 4 + r;
            if (gm < M) {
                unsigned short* hrow = SH ? hS + (size_t)gm * HSDIM
                                          : hE + (size_t)(base + gm) * HDIM;
#pragma unroll
                for (int nt = 0; nt < 2; nt++) {
                    float z1 = acc1[mt][nt][r];
                    float z2 = acc2[mt][nt][r];
                    float hv = (z1 / (1.f + __expf(-z1))) * z2;
                    hrow[n0 + wn + nt * 16 + l15] = f2bf(hv);
                }
            }
        }
    }
}

// ---------------- merged down-proj GEMM: Out += w * (H @ W3) ----------------
__global__ __launch_bounds__(256) void gemm3_kernel(
    const unsigned short* __restrict__ hE, const unsigned short* __restrict__ hS,
    const unsigned short* __restrict__ w3, const unsigned short* __restrict__ ws3,
    float* __restrict__ Out,
    const int* __restrict__ rowT, const float* __restrict__ rowW, const int* __restrict__ meta) {
    const int id = blockIdx.x;
    int z, m0, n0; bool SH;
    if (id < 1280) { SH = false; z = id & 7; int q = id >> 3; m0 = (q % 20) * 128; n0 = (q / 20) * 128; }
    else           { SH = true;  z = 8; int q = id - 1280; m0 = (q & 63) * 128; n0 = (q >> 6) * 128; }
    const int M = SH ? NTOK : meta[z];
    const int base = SH ? 0 : meta[8 + z];
    if (m0 >= M) return;
    const int K = SH ? HSDIM : HDIM;
    const unsigned short* A = SH ? hS : hE;
    const unsigned short* B = SH ? ws3 : w3 + (size_t)z * CDIM * HDIM;

    __shared__ unsigned short L[16384];

    const int tid = threadIdx.x;
    const int srow = tid >> 2;
    const int key = (tid >> 3) & 3;
    const int co = ((tid & 3) ^ key) << 3;

    int am0 = m0 + srow;       am0 = am0 < M ? am0 : M - 1;
    int am1 = m0 + 64 + srow;  am1 = am1 < M ? am1 : M - 1;
    const unsigned short* a0p = A + (size_t)(base + am0) * K + co;
    const unsigned short* a1p = A + (size_t)(base + am1) * K + co;
    const unsigned short* b0p = B + (size_t)(n0 + srow) * K + co;
    const unsigned short* b1p = B + (size_t)(n0 + 64 + srow) * K + co;

    const int w = tid >> 6, lane = tid & 63;
    const int wm = (w >> 1) * 64, wn = (w & 1) * 64;
    const int quad = lane >> 4, l15 = lane & 15;
    const int rcx = (quad ^ ((l15 >> 1) & 3)) << 3;

    f4v acc[4][4];
#pragma unroll
    for (int i = 0; i < 4; i++)
#pragma unroll
        for (int j = 0; j < 4; j++) {
            f4v zz = {0.f, 0.f, 0.f, 0.f};
            acc[i][j] = zz;
        }

    uint4 r0a0, r0a1, r0b0, r0b1;
    uint4 r1a0, r1a1, r1b0, r1b1;

#define LOADSET3(s, k0) do { \
        r##s##a0 = *(const uint4*)(a0p + (k0)); \
        r##s##a1 = *(const uint4*)(a1p + (k0)); \
        r##s##b0 = *(const uint4*)(b0p + (k0)); \
        r##s##b1 = *(const uint4*)(b1p + (k0)); } while (0)
#define WRITESET3(b, s) do { \
        *(uint4*)(L + (b) * 4096 + tid * 8) = r##s##a0; \
        *(uint4*)(L + (b) * 4096 + 2048 + tid * 8) = r##s##a1; \
        *(uint4*)(L + 8192 + (b) * 4096 + tid * 8) = r##s##b0; \
        *(uint4*)(L + 8192 + (b) * 4096 + 2048 + tid * 8) = r##s##b1; } while (0)

    auto compute = [&](int b) {
        const unsigned short* Ab = L + b * 4096;
        const unsigned short* Bb = L + 8192 + b * 4096;
        s8v af[4], bf[4];
#pragma unroll
        for (int mt = 0; mt < 4; mt++)
            af[mt] = *(const s8v*)(Ab + (wm + mt * 16 + l15) * 32 + rcx);
#pragma unroll
        for (int nt = 0; nt < 4; nt++)
            bf[nt] = *(const s8v*)(Bb + (wn + nt * 16 + l15) * 32 + rcx);
#pragma unroll
        for (int mt = 0; mt < 4; mt++)
#pragma unroll
            for (int nt = 0; nt < 4; nt++)
                acc[mt][nt] = __builtin_amdgcn_mfma_f32_16x16x32_bf16(af[mt], bf[nt], acc[mt][nt], 0, 0, 0);
    };

    const int NS = K / 32;
    LOADSET3(0, 0);
    LOADSET3(1, 32);
    WRITESET3(0, 0);
    __syncthreads();
#pragma unroll 1
    for (int ks = 0; ks < NS; ks += 2) {
        if (ks + 2 < NS) LOADSET3(0, (ks + 2) * 32);
        WRITESET3(1, 1);
        compute(0);
        __syncthreads();
        if (ks + 3 < NS) LOADSET3(1, (ks + 3) * 32);
        compute(1);
        WRITESET3(0, 0);
        __syncthreads();
    }
#undef LOADSET3
#undef WRITESET3

#pragma unroll
    for (int mt = 0; mt < 4; mt++) {
#pragma unroll
        for (int r = 0; r < 4; r++) {
            int gm = m0 + wm + mt * 16 + quad * 4 + r;
            if (gm < M) {
                int t; float wgt;
                if (SH) { t = gm; wgt = 1.f; }
                else    { int rr = base + gm; t = rowT[rr]; wgt = rowW[rr]; }
                size_t o = (size_t)t * CDIM + n0 + wn + l15;
#pragma unroll
                for (int nt = 0; nt < 4; nt++)
                    atomicAdd(&Out[o + nt * 16], wgt * acc[mt][nt][r]);
            }
        }
    }
}

// ---------------- launch ----------------

extern "C" void kernel_launch(void* const* d_in, const int* in_sizes, int n_in,
                              void* d_out, int out_size, void* d_ws, size_t ws_size,
                              hipStream_t stream) {
    const float* x   = (const float*)d_in[0];
    const float* Wg  = (const float*)d_in[1];
    const float* W1  = (const float*)d_in[2];
    const float* W2  = (const float*)d_in[3];
    const float* W3  = (const float*)d_in[4];
    const float* Ws1 = (const float*)d_in[5];
    const float* Ws2 = (const float*)d_in[6];
    const float* Ws3 = (const float*)d_in[7];
    float* out = (float*)d_out;

    char* p = (char*)d_ws;
    auto carve = [&](size_t bytes) {
        char* r = p;
        p += (bytes + 255) & ~(size_t)255;
        return r;
    };
    unsigned short* xb   = (unsigned short*)carve((size_t)NTOK * CDIM * 2);
    unsigned short* w1t  = (unsigned short*)carve((size_t)NEXP * HDIM * CDIM * 2);
    unsigned short* w2t  = (unsigned short*)carve((size_t)NEXP * HDIM * CDIM * 2);
    unsigned short* w3t  = (unsigned short*)carve((size_t)NEXP * CDIM * HDIM * 2);
    unsigned short* ws1t = (unsigned short*)carve((size_t)HSDIM * CDIM * 2);
    unsigned short* ws2t = (unsigned short*)carve((size_t)HSDIM * CDIM * 2);
    unsigned short* ws3t = (unsigned short*)carve((size_t)CDIM * HSDIM * 2);
    unsigned short* hE   = (unsigned short*)carve((size_t)2 * NTOK * HDIM * 2);
    unsigned short* hS   = (unsigned short*)carve((size_t)NTOK * HSDIM * 2);
    int*   idxK  = (int*)carve((size_t)NTOK * 2 * 4);
    float* probK = (float*)carve((size_t)NTOK * 2 * 4);
    int*   rowT  = (int*)carve((size_t)2 * NTOK * 4);
    float* rowW  = (float*)carve((size_t)2 * NTOK * 4);
    int*   meta  = (int*)carve(256);

    hipMemsetAsync(out, 0, (size_t)out_size * 4, stream);

    cvt_bf16_kernel<<<(NTOK * CDIM / 4 + 255) / 256, 256, 0, stream>>>(
        (const float4*)x, (ushort4*)xb, NTOK * CDIM / 4);
    // W1+W2: [8][1024][1408] -> [8][1408][1024]
    transpose_cvt_kernel<<<dim3(HDIM / 64, CDIM / 64, 16), 256, 0, stream>>>(
        W1, W2, w1t, w2t, CDIM, HDIM, 8);
    // W3: [8][1408][1024] -> [8][1024][1408]
    transpose_cvt_kernel<<<dim3(CDIM / 64, HDIM / 64, 8), 256, 0, stream>>>(
        W3, W3, w3t, w3t, HDIM, CDIM, 8);
    // Ws1+Ws2: [1024][2816] -> [2816][1024]
    transpose_cvt_kernel<<<dim3(HSDIM / 64, CDIM / 64, 2), 256, 0, stream>>>(
        Ws1, Ws2, ws1t, ws2t, CDIM, HSDIM, 1);
    // Ws3: [2816][1024] -> [1024][2816]
    transpose_cvt_kernel<<<dim3(CDIM / 64, HSDIM / 64, 1), 256, 0, stream>>>(
        Ws3, Ws3, ws3t, ws3t, HSDIM, CDIM, 1);

    hipMemsetAsync(meta, 0, 256, stream);
    router_kernel<<<NTOK, 64, 0, stream>>>(x, Wg, idxK, probK, meta);
    offsets_kernel<<<1, 1, 0, stream>>>(meta);
    fill_kernel<<<NTOK / 256, 256, 0, stream>>>(idxK, probK, meta, rowT, rowW);

    gemm12_kernel<<<3520 + 2816, 256, 0, stream>>>(
        xb, w1t, w2t, ws1t, ws2t, hE, hS, rowT, meta);
    gemm3_kernel<<<1280 + 512, 256, 0, stream>>>(
        hE, hS, w3t, ws3t, out, rowT, rowW, meta);
}

// Round 7
// 935.577 us; speedup vs baseline: 1.4405x; 1.0321x over previous
//
#include <hip/hip_runtime.h>
#include <cstdint>

#define NTOK 8192
#define CDIM 1024
#define HDIM 1408
#define HSDIM 2816
#define NEXP 8

typedef __attribute__((ext_vector_type(8))) short s8v;
typedef __attribute__((ext_vector_type(4))) float f4v;
typedef __attribute__((ext_vector_type(8))) unsigned short u16x8;

__device__ __forceinline__ unsigned short f2bf(float f) {
    unsigned int u = __float_as_uint(f);
    unsigned int r = (u + 0x7fffu + ((u >> 16) & 1u)) >> 16;  // RNE
    return (unsigned short)r;
}
__device__ __forceinline__ float bf2f(unsigned short u) {
    return __uint_as_float(((unsigned int)u) << 16);
}

// ---------------- conversion kernels ----------------

__global__ void cvt_bf16_kernel(const float4* __restrict__ in, ushort4* __restrict__ out, int n4) {
    int i = blockIdx.x * blockDim.x + threadIdx.x;
    if (i < n4) {
        float4 v = in[i];
        ushort4 o;
        o.x = f2bf(v.x); o.y = f2bf(v.y); o.z = f2bf(v.z); o.w = f2bf(v.w);
        out[i] = o;
    }
}

// 64x64 LDS-staged transpose+cvt: fp32 [z][R][Cc] -> bf16 [z][Cc][R].
__global__ __launch_bounds__(256) void transpose_cvt_kernel(
    const float* __restrict__ in0, const float* __restrict__ in1,
    unsigned short* __restrict__ out0, unsigned short* __restrict__ out1,
    int R, int Cc, int zsplit) {
    __shared__ float T[64][68];
    int z = blockIdx.z;
    const float* in = (z < zsplit) ? in0 : in1;
    unsigned short* out = (z < zsplit) ? out0 : out1;
    int zz = (z < zsplit) ? z : z - zsplit;
    const size_t bs = (size_t)R * Cc;
    in += zz * bs; out += zz * bs;

    const int t = threadIdx.x;
    const int r0 = blockIdx.y * 64, c0 = blockIdx.x * 64;

    {
        const int rl = t >> 2, cq = t & 3;
        const float* src = in + (size_t)(r0 + rl) * Cc + c0;
#pragma unroll
        for (int i = 0; i < 4; i++) {
            float4 v = *(const float4*)(src + (cq + 4 * i) * 4);
            *(float4*)&T[rl][(cq + 4 * i) * 4] = v;
        }
    }
    __syncthreads();
    {
        const int cl = t >> 2, rq = t & 3;
        unsigned short* dst = out + (size_t)(c0 + cl) * R + r0 + rq * 16;
        u16x8 lo, hi;
#pragma unroll
        for (int j = 0; j < 8; j++) lo[j] = f2bf(T[rq * 16 + j][cl]);
#pragma unroll
        for (int j = 0; j < 8; j++) hi[j] = f2bf(T[rq * 16 + 8 + j][cl]);
        *(u16x8*)dst = lo;
        *(u16x8*)(dst + 8) = hi;
    }
}

// ---------------- router ----------------
__global__ void router_kernel(const float* __restrict__ x, const float* __restrict__ Wg,
                              int* __restrict__ idxK, float* __restrict__ probK,
                              int* __restrict__ meta) {
    int t = blockIdx.x;
    int lane = threadIdx.x;
    const float* xr = x + (size_t)t * CDIM;
    float acc[NEXP];
#pragma unroll
    for (int e = 0; e < NEXP; e++) acc[e] = 0.f;
    for (int c = lane; c < CDIM; c += 64) {
        float xv = xr[c];
        const float* wr = Wg + c * NEXP;
#pragma unroll
        for (int e = 0; e < NEXP; e++) acc[e] += xv * wr[e];
    }
#pragma unroll
    for (int e = 0; e < NEXP; e++)
        for (int off = 32; off > 0; off >>= 1)
            acc[e] += __shfl_down(acc[e], off, 64);
    if (lane == 0) {
        int b0 = 0; float v0 = acc[0];
#pragma unroll
        for (int e = 1; e < NEXP; e++) if (acc[e] > v0) { v0 = acc[e]; b0 = e; }
        int b1 = -1; float v1 = -1e30f;
#pragma unroll
        for (int e = 0; e < NEXP; e++) if (e != b0 && acc[e] > v1) { v1 = acc[e]; b1 = e; }
        float p0 = 1.f / (1.f + __expf(v1 - v0));
        idxK[2 * t] = b0; idxK[2 * t + 1] = b1;
        probK[2 * t] = p0; probK[2 * t + 1] = 1.f - p0;
        atomicAdd(&meta[b0], 1);
        atomicAdd(&meta[b1], 1);
    }
}

// meta: [0..7] counts, [8..15] offsets, [16..23] cursor
__global__ void offsets_kernel(int* meta) {
    int s = 0;
    for (int e = 0; e < NEXP; e++) { meta[8 + e] = s; meta[16 + e] = s; s += meta[e]; }
}

__global__ void fill_kernel(const int* __restrict__ idxK, const float* __restrict__ probK,
                            int* __restrict__ meta, int* __restrict__ rowT, float* __restrict__ rowW,
                            int* __restrict__ tokSlot) {
    int t = blockIdx.x * 256 + threadIdx.x;
    if (t >= NTOK) return;
#pragma unroll
    for (int k = 0; k < 2; k++) {
        int e = idxK[2 * t + k];
        int p = atomicAdd(&meta[16 + e], 1);
        rowT[p] = t;
        rowW[p] = probK[2 * t + k];
        tokSlot[2 * t + k] = p;
    }
}

// ---------------- merged fused gate GEMM: H = silu(A@W1) * (A@W2) ----------------
// 1D grid, XCD-pinned: ids [0,3520): experts, id%8==z; ids [3520,6336): shared.
// BM=128, BN=64, BK=32. Depth-2 VGPR prefetch + ds_write staging.
__global__ __launch_bounds__(256) void gemm12_kernel(
    const unsigned short* __restrict__ xb,
    const unsigned short* __restrict__ w1, const unsigned short* __restrict__ w2,
    const unsigned short* __restrict__ ws1, const unsigned short* __restrict__ ws2,
    unsigned short* __restrict__ hE, unsigned short* __restrict__ hS,
    const int* __restrict__ rowT, const int* __restrict__ meta) {
    const int id = blockIdx.x;
    int z, m0, n0; bool SH;
    if (id < 3520) { SH = false; z = id & 7; int q = id >> 3; m0 = (q % 20) * 128; n0 = (q / 20) * 64; }
    else           { SH = true;  z = 8; int q = id - 3520; m0 = (q & 63) * 128; n0 = (q >> 6) * 64; }
    const int M = SH ? NTOK : meta[z];
    const int base = SH ? 0 : meta[8 + z];
    if (m0 >= M) return;

    const unsigned short* B1 = SH ? ws1 : w1 + (size_t)z * HDIM * CDIM;
    const unsigned short* B2 = SH ? ws2 : w2 + (size_t)z * HDIM * CDIM;

    __shared__ unsigned short L[16384];  // 32 KB

    const int tid = threadIdx.x;
    const int srow = tid >> 2;
    const int key = (tid >> 3) & 3;
    const int co = ((tid & 3) ^ key) << 3;

    int am0 = m0 + srow;       am0 = am0 < M ? am0 : M - 1;
    int am1 = m0 + 64 + srow;  am1 = am1 < M ? am1 : M - 1;
    long ar0 = SH ? am0 : rowT[base + am0];
    long ar1 = SH ? am1 : rowT[base + am1];
    const unsigned short* a0p = xb + (size_t)ar0 * CDIM + co;
    const unsigned short* a1p = xb + (size_t)ar1 * CDIM + co;
    const unsigned short* b1p = B1 + (size_t)(n0 + srow) * CDIM + co;
    const unsigned short* b2p = B2 + (size_t)(n0 + srow) * CDIM + co;

    const int w = tid >> 6, lane = tid & 63;
    const int wm = (w >> 1) * 64, wn = (w & 1) * 32;
    const int quad = lane >> 4, l15 = lane & 15;
    const int rcx = (quad ^ ((l15 >> 1) & 3)) << 3;

    f4v acc1[4][2], acc2[4][2];
#pragma unroll
    for (int i = 0; i < 4; i++)
#pragma unroll
        for (int j = 0; j < 2; j++) {
            f4v zz = {0.f, 0.f, 0.f, 0.f};
            acc1[i][j] = zz; acc2[i][j] = zz;
        }

    uint4 r0a0, r0a1, r0b1, r0b2;
    uint4 r1a0, r1a1, r1b1, r1b2;

#define LOADSET12(s, k0) do { \
        r##s##a0 = *(const uint4*)(a0p + (k0)); \
        r##s##a1 = *(const uint4*)(a1p + (k0)); \
        r##s##b1 = *(const uint4*)(b1p + (k0)); \
        r##s##b2 = *(const uint4*)(b2p + (k0)); } while (0)
#define WRITESET12(b, s) do { \
        *(uint4*)(L + (b) * 4096 + tid * 8) = r##s##a0; \
        *(uint4*)(L + (b) * 4096 + 2048 + tid * 8) = r##s##a1; \
        *(uint4*)(L + 8192 + (b) * 2048 + tid * 8) = r##s##b1; \
        *(uint4*)(L + 12288 + (b) * 2048 + tid * 8) = r##s##b2; } while (0)

    auto compute = [&](int b) {
        const unsigned short* Ab = L + b * 4096;
        const unsigned short* B1b = L + 8192 + b * 2048;
        const unsigned short* B2b = L + 12288 + b * 2048;
        s8v af[4], bf1[2], bf2[2];
#pragma unroll
        for (int mt = 0; mt < 4; mt++)
            af[mt] = *(const s8v*)(Ab + (wm + mt * 16 + l15) * 32 + rcx);
#pragma unroll
        for (int nt = 0; nt < 2; nt++) {
            bf1[nt] = *(const s8v*)(B1b + (wn + nt * 16 + l15) * 32 + rcx);
            bf2[nt] = *(const s8v*)(B2b + (wn + nt * 16 + l15) * 32 + rcx);
        }
#pragma unroll
        for (int mt = 0; mt < 4; mt++)
#pragma unroll
            for (int nt = 0; nt < 2; nt++) {
                acc1[mt][nt] = __builtin_amdgcn_mfma_f32_16x16x32_bf16(af[mt], bf1[nt], acc1[mt][nt], 0, 0, 0);
                acc2[mt][nt] = __builtin_amdgcn_mfma_f32_16x16x32_bf16(af[mt], bf2[nt], acc2[mt][nt], 0, 0, 0);
            }
    };

    const int NS = CDIM / 32;
    LOADSET12(0, 0);
    LOADSET12(1, 32);
    WRITESET12(0, 0);
    __syncthreads();
#pragma unroll 1
    for (int ks = 0; ks < NS; ks += 2) {
        if (ks + 2 < NS) LOADSET12(0, (ks + 2) * 32);
        WRITESET12(1, 1);
        compute(0);
        __syncthreads();
        if (ks + 3 < NS) LOADSET12(1, (ks + 3) * 32);
        compute(1);
        WRITESET12(0, 0);
        __syncthreads();
    }
#undef LOADSET12
#undef WRITESET12

#pragma unroll
    for (int mt = 0; mt < 4; mt++) {
#pragma unroll
        for (int r = 0; r < 4; r++) {
            int gm = m0 + wm + mt * 16 + quad * 4 + r;
            if (gm < M) {
                unsigned short* hrow = SH ? hS + (size_t)gm * HSDIM
                                          : hE + (size_t)(base + gm) * HDIM;
#pragma unroll
                for (int nt = 0; nt < 2; nt++) {
                    float z1 = acc1[mt][nt][r];
                    float z2 = acc2[mt][nt][r];
                    float hv = (z1 / (1.f + __expf(-z1))) * z2;
                    hrow[n0 + wn + nt * 16 + l15] = f2bf(hv);
                }
            }
        }
    }
}

// ---------------- merged down-proj GEMM ----------------
// z<8: expert -> PLAIN bf16 stores to pE[slot][c] (no atomics).
// z==8: shared -> plain fp32 stores directly to Out (covers every element).
__global__ __launch_bounds__(256) void gemm3_kernel(
    const unsigned short* __restrict__ hE, const unsigned short* __restrict__ hS,
    const unsigned short* __restrict__ w3, const unsigned short* __restrict__ ws3,
    float* __restrict__ Out, unsigned short* __restrict__ pE,
    const int* __restrict__ rowT, const float* __restrict__ rowW, const int* __restrict__ meta) {
    const int id = blockIdx.x;
    int z, m0, n0; bool SH;
    if (id < 1280) { SH = false; z = id & 7; int q = id >> 3; m0 = (q % 20) * 128; n0 = (q / 20) * 128; }
    else           { SH = true;  z = 8; int q = id - 1280; m0 = (q & 63) * 128; n0 = (q >> 6) * 128; }
    const int M = SH ? NTOK : meta[z];
    const int base = SH ? 0 : meta[8 + z];
    if (m0 >= M) return;
    const int K = SH ? HSDIM : HDIM;
    const unsigned short* A = SH ? hS : hE;
    const unsigned short* B = SH ? ws3 : w3 + (size_t)z * CDIM * HDIM;

    __shared__ unsigned short L[16384];

    const int tid = threadIdx.x;
    const int srow = tid >> 2;
    const int key = (tid >> 3) & 3;
    const int co = ((tid & 3) ^ key) << 3;

    int am0 = m0 + srow;       am0 = am0 < M ? am0 : M - 1;
    int am1 = m0 + 64 + srow;  am1 = am1 < M ? am1 : M - 1;
    const unsigned short* a0p = A + (size_t)(base + am0) * K + co;
    const unsigned short* a1p = A + (size_t)(base + am1) * K + co;
    const unsigned short* b0p = B + (size_t)(n0 + srow) * K + co;
    const unsigned short* b1p = B + (size_t)(n0 + 64 + srow) * K + co;

    const int w = tid >> 6, lane = tid & 63;
    const int wm = (w >> 1) * 64, wn = (w & 1) * 64;
    const int quad = lane >> 4, l15 = lane & 15;
    const int rcx = (quad ^ ((l15 >> 1) & 3)) << 3;

    f4v acc[4][4];
#pragma unroll
    for (int i = 0; i < 4; i++)
#pragma unroll
        for (int j = 0; j < 4; j++) {
            f4v zz = {0.f, 0.f, 0.f, 0.f};
            acc[i][j] = zz;
        }

    uint4 r0a0, r0a1, r0b0, r0b1;
    uint4 r1a0, r1a1, r1b0, r1b1;

#define LOADSET3(s, k0) do { \
        r##s##a0 = *(const uint4*)(a0p + (k0)); \
        r##s##a1 = *(const uint4*)(a1p + (k0)); \
        r##s##b0 = *(const uint4*)(b0p + (k0)); \
        r##s##b1 = *(const uint4*)(b1p + (k0)); } while (0)
#define WRITESET3(b, s) do { \
        *(uint4*)(L + (b) * 4096 + tid * 8) = r##s##a0; \
        *(uint4*)(L + (b) * 4096 + 2048 + tid * 8) = r##s##a1; \
        *(uint4*)(L + 8192 + (b) * 4096 + tid * 8) = r##s##b0; \
        *(uint4*)(L + 8192 + (b) * 4096 + 2048 + tid * 8) = r##s##b1; } while (0)

    auto compute = [&](int b) {
        const unsigned short* Ab = L + b * 4096;
        const unsigned short* Bb = L + 8192 + b * 4096;
        s8v af[4], bf[4];
#pragma unroll
        for (int mt = 0; mt < 4; mt++)
            af[mt] = *(const s8v*)(Ab + (wm + mt * 16 + l15) * 32 + rcx);
#pragma unroll
        for (int nt = 0; nt < 4; nt++)
            bf[nt] = *(const s8v*)(Bb + (wn + nt * 16 + l15) * 32 + rcx);
#pragma unroll
        for (int mt = 0; mt < 4; mt++)
#pragma unroll
            for (int nt = 0; nt < 4; nt++)
                acc[mt][nt] = __builtin_amdgcn_mfma_f32_16x16x32_bf16(af[mt], bf[nt], acc[mt][nt], 0, 0, 0);
    };

    const int NS = K / 32;
    LOADSET3(0, 0);
    LOADSET3(1, 32);
    WRITESET3(0, 0);
    __syncthreads();
#pragma unroll 1
    for (int ks = 0; ks < NS; ks += 2) {
        if (ks + 2 < NS) LOADSET3(0, (ks + 2) * 32);
        WRITESET3(1, 1);
        compute(0);
        __syncthreads();
        if (ks + 3 < NS) LOADSET3(1, (ks + 3) * 32);
        compute(1);
        WRITESET3(0, 0);
        __syncthreads();
    }
#undef LOADSET3
#undef WRITESET3

#pragma unroll
    for (int mt = 0; mt < 4; mt++) {
#pragma unroll
        for (int r = 0; r < 4; r++) {
            int gm = m0 + wm + mt * 16 + quad * 4 + r;
            if (gm < M) {
                if (SH) {
                    size_t o = (size_t)gm * CDIM + n0 + wn + l15;
#pragma unroll
                    for (int nt = 0; nt < 4; nt++)
                        Out[o + nt * 16] = acc[mt][nt][r];
                } else {
                    size_t o = (size_t)(base + gm) * CDIM + n0 + wn + l15;
#pragma unroll
                    for (int nt = 0; nt < 4; nt++)
                        pE[o + nt * 16] = f2bf(acc[mt][nt][r]);
                }
            }
        }
    }
}

// ---------------- combine: out[t] += w0*pE[s0] + w1*pE[s1] ----------------
__global__ __launch_bounds__(256) void combine_kernel(
    float* __restrict__ Out, const unsigned short* __restrict__ pE,
    const int* __restrict__ tokSlot, const float* __restrict__ rowW) {
    const int t = blockIdx.x;
    const int c = threadIdx.x * 4;
    const int s0 = tokSlot[2 * t], s1 = tokSlot[2 * t + 1];
    const float w0 = rowW[s0], w1 = rowW[s1];
    float* op = Out + (size_t)t * CDIM + c;
    float4 o = *(float4*)op;
    ushort4 a = *(const ushort4*)(pE + (size_t)s0 * CDIM + c);
    ushort4 b = *(const ushort4*)(pE + (size_t)s1 * CDIM + c);
    o.x += w0 * bf2f(a.x) + w1 * bf2f(b.x);
    o.y += w0 * bf2f(a.y) + w1 * bf2f(b.y);
    o.z += w0 * bf2f(a.z) + w1 * bf2f(b.z);
    o.w += w0 * bf2f(a.w) + w1 * bf2f(b.w);
    *(float4*)op = o;
}

// ---------------- launch ----------------

extern "C" void kernel_launch(void* const* d_in, const int* in_sizes, int n_in,
                              void* d_out, int out_size, void* d_ws, size_t ws_size,
                              hipStream_t stream) {
    const float* x   = (const float*)d_in[0];
    const float* Wg  = (const float*)d_in[1];
    const float* W1  = (const float*)d_in[2];
    const float* W2  = (const float*)d_in[3];
    const float* W3  = (const float*)d_in[4];
    const float* Ws1 = (const float*)d_in[5];
    const float* Ws2 = (const float*)d_in[6];
    const float* Ws3 = (const float*)d_in[7];
    float* out = (float*)d_out;

    char* p = (char*)d_ws;
    auto carve = [&](size_t bytes) {
        char* r = p;
        p += (bytes + 255) & ~(size_t)255;
        return r;
    };
    unsigned short* xb   = (unsigned short*)carve((size_t)NTOK * CDIM * 2);
    unsigned short* w1t  = (unsigned short*)carve((size_t)NEXP * HDIM * CDIM * 2);
    unsigned short* w2t  = (unsigned short*)carve((size_t)NEXP * HDIM * CDIM * 2);
    unsigned short* w3t  = (unsigned short*)carve((size_t)NEXP * CDIM * HDIM * 2);
    unsigned short* ws1t = (unsigned short*)carve((size_t)HSDIM * CDIM * 2);
    unsigned short* ws2t = (unsigned short*)carve((size_t)HSDIM * CDIM * 2);
    unsigned short* ws3t = (unsigned short*)carve((size_t)CDIM * HSDIM * 2);
    unsigned short* hE   = (unsigned short*)carve((size_t)2 * NTOK * HDIM * 2);
    unsigned short* hS   = (unsigned short*)carve((size_t)NTOK * HSDIM * 2);
    int*   idxK   = (int*)carve((size_t)NTOK * 2 * 4);
    float* probK  = (float*)carve((size_t)NTOK * 2 * 4);
    int*   rowT   = (int*)carve((size_t)2 * NTOK * 4);
    float* rowW   = (float*)carve((size_t)2 * NTOK * 4);
    int*   tokSlot= (int*)carve((size_t)2 * NTOK * 4);
    int*   meta   = (int*)carve(256);

    // expert partials (bf16, 2N x C = 33.5 MB) alias the w1t+w2t region,
    // which is dead after gemm12 completes (stream-ordered before gemm3).
    unsigned short* pE = w1t;

    cvt_bf16_kernel<<<(NTOK * CDIM / 4 + 255) / 256, 256, 0, stream>>>(
        (const float4*)x, (ushort4*)xb, NTOK * CDIM / 4);
    transpose_cvt_kernel<<<dim3(HDIM / 64, CDIM / 64, 16), 256, 0, stream>>>(
        W1, W2, w1t, w2t, CDIM, HDIM, 8);
    transpose_cvt_kernel<<<dim3(CDIM / 64, HDIM / 64, 8), 256, 0, stream>>>(
        W3, W3, w3t, w3t, HDIM, CDIM, 8);
    transpose_cvt_kernel<<<dim3(HSDIM / 64, CDIM / 64, 2), 256, 0, stream>>>(
        Ws1, Ws2, ws1t, ws2t, CDIM, HSDIM, 1);
    transpose_cvt_kernel<<<dim3(CDIM / 64, HSDIM / 64, 1), 256, 0, stream>>>(
        Ws3, Ws3, ws3t, ws3t, HSDIM, CDIM, 1);

    hipMemsetAsync(meta, 0, 256, stream);
    router_kernel<<<NTOK, 64, 0, stream>>>(x, Wg, idxK, probK, meta);
    offsets_kernel<<<1, 1, 0, stream>>>(meta);
    fill_kernel<<<NTOK / 256, 256, 0, stream>>>(idxK, probK, meta, rowT, rowW, tokSlot);

    gemm12_kernel<<<3520 + 2816, 256, 0, stream>>>(
        xb, w1t, w2t, ws1t, ws2t, hE, hS, rowT, meta);
    gemm3_kernel<<<1280 + 512, 256, 0, stream>>>(
        hE, hS, w3t, ws3t, out, pE, rowT, rowW, meta);
    combine_kernel<<<NTOK, 256, 0, stream>>>(out, pE, tokSlot, rowW);
}